// Round 8
// baseline (333.548 us; speedup 1.0000x reference)
//
#include <hip/hip_runtime.h>

// ---------------------------------------------------------------------------
// Problem constants
// ---------------------------------------------------------------------------
#define V_PREV 16384
#define V_NEXT 65536
#define F_IN   512
#define F_OUT  256
#define NNZ_UP 65536
#define N_EDGE 524288

using f32x4 = __attribute__((ext_vector_type(4))) float;
using bfrag = __attribute__((ext_vector_type(8))) short;   // 8 x bf16

__device__ __forceinline__ ushort f2bf(float f) {
    union { float f; unsigned u; } v; v.f = f;
    unsigned r = (v.u + 0x7FFFu + ((v.u >> 16) & 1u)) >> 16;
    return (ushort)r;
}
__device__ __forceinline__ float bf2f(ushort h) {
    union { unsigned u; float f; } v; v.u = ((unsigned)h) << 16; return v.f;
}

// ---------------------------------------------------------------------------
// Weight prep:
//   WresT [256][512] = W_res^T
//   W0t   [512][512] = [Uj0 | Ui0]^T
//   W1cat [256][512] : k<256 -> Ui1^T, k>=256 -> Uj1^T   (for [H1|G] @ .)
//   biasUi[256] = Ui1_b + b_res
// ---------------------------------------------------------------------------
__global__ void prep_weights_kernel(const float* __restrict__ Wres,
                                    const float* __restrict__ Ui0W, const float* __restrict__ Uj0W,
                                    const float* __restrict__ Ui1W, const float* __restrict__ Uj1W,
                                    const float* __restrict__ Ui1b, const float* __restrict__ bres,
                                    ushort* __restrict__ WresT, ushort* __restrict__ W0t,
                                    ushort* __restrict__ W1cat, float* __restrict__ biasUi)
{
    int i = blockIdx.x * blockDim.x + threadIdx.x;   // 0 .. 512*512-1
    if (i < 256 * 512) {
        int n = i / 512, k = i % 512;
        WresT[i] = f2bf(Wres[k * 256 + n]);
        W1cat[i] = f2bf(k < 256 ? Ui1W[k * 256 + n] : Uj1W[(k - 256) * 256 + n]);
    }
    if (i < 512 * 512) {
        int n = i / 512, k = i % 512;
        W0t[i] = f2bf(n < 256 ? Uj0W[k * 256 + n] : Ui0W[k * 256 + (n - 256)]);
    }
    if (i < 256) biasUi[i] = Ui1b[i] + bres[i];
}

// ---------------------------------------------------------------------------
// Up-map invert + CSR build
// ---------------------------------------------------------------------------
__global__ void invert_up_kernel(const int* __restrict__ up_row, const int* __restrict__ up_col,
                                 const float* __restrict__ up_val,
                                 int* __restrict__ colof, float* __restrict__ valof)
{
    int k = blockIdx.x * blockDim.x + threadIdx.x;
    int r = up_row[k];
    colof[r] = up_col[k];
    valof[r] = up_val[k];
}

__global__ void hist_kernel(const int* __restrict__ dst, const float* __restrict__ adjv,
                            int* __restrict__ cnt, float* __restrict__ sumA)
{
    int e = blockIdx.x * blockDim.x + threadIdx.x;
    int d = dst[e];
    atomicAdd(&cnt[d], 1);
    atomicAdd(&sumA[d], adjv[e]);
}

__global__ void scan_block_kernel(const int* __restrict__ cnt, int* __restrict__ offs,
                                  int* __restrict__ bsum)
{
    __shared__ int buf[2][256];
    int t = threadIdx.x;
    int i = blockIdx.x * 256 + t;
    int v = cnt[i];
    int p = 0;
    buf[0][t] = v;
    __syncthreads();
    for (int d = 1; d < 256; d <<= 1) {
        int nv = buf[p][t] + ((t >= d) ? buf[p][t - d] : 0);
        buf[p ^ 1][t] = nv;
        p ^= 1;
        __syncthreads();
    }
    int incl = buf[p][t];
    offs[i] = incl - v;
    if (t == 255) bsum[blockIdx.x] = incl;
}

__global__ void scan_top_kernel(const int* __restrict__ bsum, int* __restrict__ boff)
{
    __shared__ int buf[2][256];
    int t = threadIdx.x;
    int v = bsum[t];
    int p = 0;
    buf[0][t] = v;
    __syncthreads();
    for (int d = 1; d < 256; d <<= 1) {
        int nv = buf[p][t] + ((t >= d) ? buf[p][t - d] : 0);
        buf[p ^ 1][t] = nv;
        p ^= 1;
        __syncthreads();
    }
    boff[t] = buf[p][t] - v;
}

__global__ void add_offs_kernel(int* __restrict__ offs, const int* __restrict__ boff,
                                int* __restrict__ cursor)
{
    int i = blockIdx.x * 256 + threadIdx.x;
    int o = offs[i] + boff[blockIdx.x];
    offs[i] = o;
    cursor[i] = o;
}

// dst-sorted edges; layer-0 variant pre-composes the up map
__global__ void fill_kernel(const int* __restrict__ src, const int* __restrict__ dst,
                            const float* __restrict__ adjv,
                            const int* __restrict__ colof, const float* __restrict__ valof,
                            int* __restrict__ cursor,
                            int* __restrict__ srcsA, float* __restrict__ valsA,
                            int* __restrict__ srcs0, float* __restrict__ vals0)
{
    int e = blockIdx.x * blockDim.x + threadIdx.x;
    int d = dst[e];
    int s = src[e];
    float a = adjv[e];
    int p = atomicAdd(&cursor[d], 1);
    srcsA[p] = s;
    valsA[p] = a;
    srcs0[p] = colof[s];
    vals0[p] = a * valof[s];
}

// ---------------------------------------------------------------------------
// BatchNorm stats (bn0)
// ---------------------------------------------------------------------------
__global__ void bn0_part_kernel(const float* __restrict__ x,
                                float* __restrict__ psum, float* __restrict__ psq)
{
    int blk = blockIdx.x, t = threadIdx.x;
    float s0 = 0, s1 = 0, q0 = 0, q1 = 0;
    for (int r = 0; r < 128; r++) {
        size_t base = ((size_t)blk * 128 + r) * 512;
        float a = x[base + t], b = x[base + t + 256];
        s0 += a; q0 += a * a; s1 += b; q1 += b * b;
    }
    psum[blk * 512 + t] = s0; psum[blk * 512 + t + 256] = s1;
    psq [blk * 512 + t] = q0; psq [blk * 512 + t + 256] = q1;
}

// Parallel finish: one wave per channel; produces sc = g*rstd, sh = b - mean*sc
__global__ void bn_finish_kernel(const float* __restrict__ psum, const float* __restrict__ psq,
                                 int nblocks, int C, float invN,
                                 const float* __restrict__ g, const float* __restrict__ b,
                                 float* __restrict__ sc, float* __restrict__ sh)
{
    int gw = (blockIdx.x * blockDim.x + threadIdx.x) >> 6;   // channel
    int lane = threadIdx.x & 63;
    if (gw >= C) return;
    float s = 0, q = 0;
    for (int i = lane; i < nblocks; i += 64) {
        s += psum[(size_t)i * C + gw];
        q += psq [(size_t)i * C + gw];
    }
#pragma unroll
    for (int d = 32; d > 0; d >>= 1) {
        s += __shfl_xor(s, d);
        q += __shfl_xor(q, d);
    }
    if (lane == 0) {
        float m = s * invN;
        float v = q * invN - m * m;
        float r = rsqrtf(v + 1e-5f);
        float scale = r * g[gw];
        sc[gw] = scale;
        sh[gw] = b[gw] - m * scale;
    }
}

// ---------------------------------------------------------------------------
// GEMM0 fused: reads x f32 [16384,512] directly. 1D grid 768, XCD-grouped.
//   bx 0,1: XW  = bf16(x) @ WresT^T
//   bx 2,3: XNJ = relu(bn0(x)) @ Uj0
//   bx 4,5: XNI = relu(bn0(x)) @ Ui0
// LDS linear [row][32 shorts/unit4] + XOR unit^(row&3): conflict-free.
// ---------------------------------------------------------------------------
__global__ __launch_bounds__(256)
void gemm0_fused_kernel(const float* __restrict__ x,
                        const ushort* __restrict__ WresT, const ushort* __restrict__ W0t,
                        const float* __restrict__ sc0, const float* __restrict__ sh0,
                        ushort* __restrict__ XW, ushort* __restrict__ XNJ,
                        ushort* __restrict__ XNI)
{
    __shared__ ushort As[128 * 32];
    __shared__ ushort Bs[128 * 32];
    __shared__ float s_sc[512], s_sh[512];

    const int tid = threadIdx.x;
    const int id   = blockIdx.x;
    const int xcd  = id & 7;
    const int rest = id >> 3;
    const int slot = rest / 6;
    const int bx   = rest - slot * 6;
    const int by   = slot * 8 + xcd;

    const bool bnmode = bx >= 2;
    const ushort* Bt = bnmode ? W0t : WresT;
    const int btrow = bnmode ? (bx - 2) * 128 : bx * 128;
    ushort* Cout = (bx < 2) ? XW : (bx < 4 ? XNJ : XNI);
    const int colbase = (bx & 1) * 128;
    const int tM = by * 128;

    for (int i = tid; i < 512; i += 256) { s_sc[i] = sc0[i]; s_sh[i] = sh0[i]; }
    __syncthreads();

    const int lane = tid & 63;
    const int wave = tid >> 6;
    const int wm = wave >> 1, wn = wave & 1;
    const int lr = lane & 15, lg = lane >> 4;

    const int ra = tid >> 1;
    const int ua = (tid & 1) * 2;
    const int rb = tid >> 2;
    const int ub = tid & 3;

    f32x4 acc[4][4] = {};

    for (int k0 = 0; k0 < 512; k0 += 32) {
        const float* xp = &x[(size_t)(tM + ra) * 512 + k0 + ua * 8];
        float4 f0 = *(const float4*)(xp);
        float4 f1 = *(const float4*)(xp + 4);
        float4 f2 = *(const float4*)(xp + 8);
        float4 f3 = *(const float4*)(xp + 12);
        float vv[16] = { f0.x,f0.y,f0.z,f0.w, f1.x,f1.y,f1.z,f1.w,
                         f2.x,f2.y,f2.z,f2.w, f3.x,f3.y,f3.z,f3.w };
        ushort hh[16];
        if (bnmode) {
#pragma unroll
            for (int j = 0; j < 16; j++) {
                int c = k0 + ua * 8 + j;
                hh[j] = f2bf(fmaxf(vv[j] * s_sc[c] + s_sh[c], 0.0f));
            }
        } else {
#pragma unroll
            for (int j = 0; j < 16; j++) hh[j] = f2bf(vv[j]);
        }
        *(uint4*)&As[ra * 32 + ((ua    ) ^ (ra & 3)) * 8] = *(uint4*)&hh[0];
        *(uint4*)&As[ra * 32 + ((ua + 1) ^ (ra & 3)) * 8] = *(uint4*)&hh[8];

#pragma unroll
        for (int i = 0; i < 2; i++) {
            int row = rb + i * 64;
            *(uint4*)&Bs[row * 32 + (ub ^ (row & 3)) * 8] =
                *(const uint4*)&Bt[(size_t)(btrow + row) * 512 + k0 + ub * 8];
        }
        __syncthreads();

        bfrag af[4], bfv[4];
#pragma unroll
        for (int mm = 0; mm < 4; mm++) {
            int row = wm * 64 + mm * 16 + lr;
            af[mm] = *(const bfrag*)&As[row * 32 + (lg ^ (row & 3)) * 8];
        }
#pragma unroll
        for (int nn = 0; nn < 4; nn++) {
            int row = wn * 64 + nn * 16 + lr;
            bfv[nn] = *(const bfrag*)&Bs[row * 32 + (lg ^ (row & 3)) * 8];
        }
#pragma unroll
        for (int mm = 0; mm < 4; mm++)
#pragma unroll
            for (int nn = 0; nn < 4; nn++)
                acc[mm][nn] = __builtin_amdgcn_mfma_f32_16x16x32_bf16(af[mm], bfv[nn], acc[mm][nn], 0, 0, 0);
        __syncthreads();
    }

#pragma unroll
    for (int mm = 0; mm < 4; mm++)
#pragma unroll
        for (int nn = 0; nn < 4; nn++)
#pragma unroll
            for (int r = 0; r < 4; r++) {
                int row = tM + wm * 64 + mm * 16 + lg * 4 + r;
                int col = colbase + wn * 64 + nn * 16 + lr;
                Cout[(size_t)row * 256 + col] = f2bf(acc[mm][nn][r]);
            }
}

// ---------------------------------------------------------------------------
// Gather layer 0 + fused bn1 partial stats:
//   X1[d] = ui0_b + valof[d]*XNI[colof[d]] + sumA[d]*uj0_b + sum vals0*XNJ[srcs0]
//   psum1s/psq1s[blockIdx&63][c] += block partials (LDS-reduced, 2 atomics/thr)
// ---------------------------------------------------------------------------
__global__ __launch_bounds__(256)
void gather0_kernel(const int* __restrict__ offs, const int* __restrict__ cnt,
                    const int* __restrict__ srcs0, const float* __restrict__ vals0,
                    const int* __restrict__ colof, const float* __restrict__ valof,
                    const float* __restrict__ sumA,
                    const ushort* __restrict__ XNJ, const ushort* __restrict__ XNI,
                    const float* __restrict__ ui_b, const float* __restrict__ uj_b,
                    ushort* __restrict__ X1,
                    float* __restrict__ psum1s, float* __restrict__ psq1s)
{
    __shared__ float redS[4][256];
    __shared__ float redQ[4][256];

    int wave = threadIdx.x >> 6;
    int d = blockIdx.x * 4 + wave;
    int f = (threadIdx.x & 63) * 4;
    int c = colof[d];
    float s = valof[d];
    float sA = sumA[d];
    ushort4 u = *(const ushort4*)&XNI[(size_t)c * 256 + f];
    const ushort* up = (const ushort*)&u;
    float a0 = ui_b[f + 0] + sA * uj_b[f + 0] + s * bf2f(up[0]);
    float a1 = ui_b[f + 1] + sA * uj_b[f + 1] + s * bf2f(up[1]);
    float a2 = ui_b[f + 2] + sA * uj_b[f + 2] + s * bf2f(up[2]);
    float a3 = ui_b[f + 3] + sA * uj_b[f + 3] + s * bf2f(up[3]);

    int st = offs[d], n = cnt[d];
    if (n > 0) {
        int   sc = srcs0[st];
        float ac = vals0[st];
        ushort4 vc = *(const ushort4*)&XNJ[(size_t)sc * 256 + f];
        for (int e = 1; e < n; e++) {
            int   sn = srcs0[st + e];
            float an = vals0[st + e];
            ushort4 vn = *(const ushort4*)&XNJ[(size_t)sn * 256 + f];
            const ushort* vp = (const ushort*)&vc;
            a0 += ac * bf2f(vp[0]); a1 += ac * bf2f(vp[1]);
            a2 += ac * bf2f(vp[2]); a3 += ac * bf2f(vp[3]);
            vc = vn; ac = an;
        }
        const ushort* vp = (const ushort*)&vc;
        a0 += ac * bf2f(vp[0]); a1 += ac * bf2f(vp[1]);
        a2 += ac * bf2f(vp[2]); a3 += ac * bf2f(vp[3]);
    }
    *(ushort4*)&X1[(size_t)d * 256 + f] =
        make_ushort4(f2bf(a0), f2bf(a1), f2bf(a2), f2bf(a3));

    // bn1 partial stats
    redS[wave][f + 0] = a0; redS[wave][f + 1] = a1;
    redS[wave][f + 2] = a2; redS[wave][f + 3] = a3;
    redQ[wave][f + 0] = a0 * a0; redQ[wave][f + 1] = a1 * a1;
    redQ[wave][f + 2] = a2 * a2; redQ[wave][f + 3] = a3 * a3;
    __syncthreads();
    int t = threadIdx.x;   // channel
    float ssum = redS[0][t] + redS[1][t] + redS[2][t] + redS[3][t];
    float sq   = redQ[0][t] + redQ[1][t] + redQ[2][t] + redQ[3][t];
    int slab = (blockIdx.x & 63) * 256 + t;
    atomicAdd(&psum1s[slab], ssum);
    atomicAdd(&psq1s[slab], sq);
}

// ---------------------------------------------------------------------------
// GEMM final FUSED: per block of 64 rows,
//   phase 1: gather G rows into LDS:  G[d] = sum valsA * relu(bn1(X1[srcsA]))
//   phase 2: out = [relu(bn1(X1)) | G] @ W1cat^T + biasUi + sumA*Uj1_b + residual
// 512 threads (8 waves, 2x4), grid 1024. LDS: Gp 32K + As 4K + Bs 16K + 2K.
// ---------------------------------------------------------------------------
__global__ __launch_bounds__(512, 4)
void gemm_final_fused_kernel(const ushort* __restrict__ X1, const ushort* __restrict__ W1cat,
                             const float* __restrict__ sc1, const float* __restrict__ sh1,
                             const float* __restrict__ biasUi, const float* __restrict__ uj1_b,
                             const float* __restrict__ sumA,
                             const int* __restrict__ offs, const int* __restrict__ cnt,
                             const int* __restrict__ srcsA, const float* __restrict__ valsA,
                             const int* __restrict__ colof, const float* __restrict__ valof,
                             const ushort* __restrict__ XW,
                             float* __restrict__ out)
{
    __shared__ ushort Gp[64 * 256];   // 32 KB, full G half of A, swizzled
    __shared__ ushort As[64 * 32];    // 4 KB, per-BK X1 half
    __shared__ ushort Bs[256 * 32];   // 16 KB
    __shared__ float s_sc[256], s_sh[256];

    const int tid = threadIdx.x;
    const int tM = blockIdx.x * 64;
    if (tid < 256) { s_sc[tid] = sc1[tid]; s_sh[tid] = sh1[tid]; }
    __syncthreads();

    const int lane = tid & 63;
    const int wave = tid >> 6;        // 0..7

    // ---- phase 1: gather Gp (8 rows per wave) ----
    {
        const int f = lane * 4;
        const float c0 = s_sc[f], c1 = s_sc[f + 1], c2 = s_sc[f + 2], c3 = s_sc[f + 3];
        const float h0 = s_sh[f], h1 = s_sh[f + 1], h2 = s_sh[f + 2], h3 = s_sh[f + 3];
        for (int i = 0; i < 8; i++) {
            int r = wave * 8 + i;
            int d = tM + r;
            float a0 = 0, a1 = 0, a2 = 0, a3 = 0;
            int st = offs[d], n = cnt[d];
            if (n > 0) {
                int   sv0 = srcsA[st];
                float w0 = valsA[st];
                ushort4 v0 = *(const ushort4*)&X1[(size_t)sv0 * 256 + f];
                ushort4 v1; float w1 = 0;
                if (n > 1) {
                    int sv1 = srcsA[st + 1];
                    w1 = valsA[st + 1];
                    v1 = *(const ushort4*)&X1[(size_t)sv1 * 256 + f];
                }
                for (int e = 0; e + 2 < n; e++) {
                    int   sv2 = srcsA[st + e + 2];
                    float w2 = valsA[st + e + 2];
                    ushort4 v2 = *(const ushort4*)&X1[(size_t)sv2 * 256 + f];
                    const ushort* vp = (const ushort*)&v0;
                    a0 += w0 * fmaxf(bf2f(vp[0]) * c0 + h0, 0.0f);
                    a1 += w0 * fmaxf(bf2f(vp[1]) * c1 + h1, 0.0f);
                    a2 += w0 * fmaxf(bf2f(vp[2]) * c2 + h2, 0.0f);
                    a3 += w0 * fmaxf(bf2f(vp[3]) * c3 + h3, 0.0f);
                    v0 = v1; w0 = w1; v1 = v2; w1 = w2;
                }
                if (n > 1) {
                    const ushort* vp = (const ushort*)&v0;
                    a0 += w0 * fmaxf(bf2f(vp[0]) * c0 + h0, 0.0f);
                    a1 += w0 * fmaxf(bf2f(vp[1]) * c1 + h1, 0.0f);
                    a2 += w0 * fmaxf(bf2f(vp[2]) * c2 + h2, 0.0f);
                    a3 += w0 * fmaxf(bf2f(vp[3]) * c3 + h3, 0.0f);
                    v0 = v1; w0 = w1;
                }
                const ushort* vp = (const ushort*)&v0;
                a0 += w0 * fmaxf(bf2f(vp[0]) * c0 + h0, 0.0f);
                a1 += w0 * fmaxf(bf2f(vp[1]) * c1 + h1, 0.0f);
                a2 += w0 * fmaxf(bf2f(vp[2]) * c2 + h2, 0.0f);
                a3 += w0 * fmaxf(bf2f(vp[3]) * c3 + h3, 0.0f);
            }
            // store swizzled: 16B unit index = lane>>1, su = unit ^ (r&7)
            int su = (lane >> 1) ^ (r & 7);
            *(ushort4*)((char*)Gp + (size_t)r * 512 + su * 16 + (lane & 1) * 8) =
                make_ushort4(f2bf(a0), f2bf(a1), f2bf(a2), f2bf(a3));
        }
    }
    __syncthreads();

    // ---- phase 2: GEMM ----
    const int wm = wave >> 2, wn = wave & 3;    // wave tile 32 rows x 64 cols
    const int lr = lane & 15, lg = lane >> 4;

    f32x4 acc[2][4] = {};

    for (int kc = 0; kc < 16; kc++) {
        if (kc < 8 && tid < 256) {
            // As stage: X1 half with bn+relu, 64 rows x 4 units
            int rA = tid >> 2, uA = tid & 3;
            ushort h[8];
            *(uint4*)h = *(const uint4*)&X1[(size_t)(tM + rA) * 256 + kc * 32 + uA * 8];
#pragma unroll
            for (int j = 0; j < 8; j++) {
                int cch = kc * 32 + uA * 8 + j;
                h[j] = f2bf(fmaxf(bf2f(h[j]) * s_sc[cch] + s_sh[cch], 0.0f));
            }
            *(uint4*)&As[rA * 32 + ((uA ^ (rA & 3)) * 8)] = *(uint4*)h;
        }
        // Bs stage: 256 rows x 4 units, 2 per thread
#pragma unroll
        for (int i = 0; i < 2; i++) {
            int idx = tid + i * 512;
            int row = idx >> 2, u = idx & 3;
            *(uint4*)&Bs[row * 32 + ((u ^ (row & 3)) * 8)] =
                *(const uint4*)&W1cat[(size_t)row * 512 + kc * 32 + u * 8];
        }
        __syncthreads();

        bfrag af[2], bfv[4];
#pragma unroll
        for (int mm = 0; mm < 2; mm++) {
            int row = wm * 32 + mm * 16 + lr;
            if (kc < 8) {
                af[mm] = *(const bfrag*)&As[row * 32 + ((lg ^ (row & 3)) * 8)];
            } else {
                int gu = (kc - 8) * 4 + lg;
                int su = gu ^ (row & 7);
                af[mm] = *(const bfrag*)&Gp[row * 256 + su * 8];
            }
        }
#pragma unroll
        for (int nn = 0; nn < 4; nn++) {
            int row = wn * 64 + nn * 16 + lr;
            bfv[nn] = *(const bfrag*)&Bs[row * 32 + ((lg ^ (row & 3)) * 8)];
        }
#pragma unroll
        for (int mm = 0; mm < 2; mm++)
#pragma unroll
            for (int nn = 0; nn < 4; nn++)
                acc[mm][nn] = __builtin_amdgcn_mfma_f32_16x16x32_bf16(af[mm], bfv[nn], acc[mm][nn], 0, 0, 0);
        __syncthreads();
    }

    // ---- epilogue ----
    float bUi[4], bUj[4];
#pragma unroll
    for (int nn = 0; nn < 4; nn++) {
        int col = wn * 64 + nn * 16 + lr;
        bUi[nn] = biasUi[col];
        bUj[nn] = uj1_b[col];
    }
#pragma unroll
    for (int mm = 0; mm < 2; mm++) {
#pragma unroll
        for (int r = 0; r < 4; r++) {
            int row = tM + wm * 32 + mm * 16 + lg * 4 + r;
            int c = colof[row];
            float s = valof[row];
            float sA = sumA[row];
#pragma unroll
            for (int nn = 0; nn < 4; nn++) {
                int col = wn * 64 + nn * 16 + lr;
                float v = acc[mm][nn][r] + bUi[nn] + sA * bUj[nn]
                        + s * bf2f(XW[(size_t)c * 256 + col]);
                out[(size_t)row * 256 + col] = v;
            }
        }
    }
}

// ---------------------------------------------------------------------------
// Host launcher
// ---------------------------------------------------------------------------
extern "C" void kernel_launch(void* const* d_in, const int* in_sizes, int n_in,
                              void* d_out, int out_size, void* d_ws, size_t ws_size,
                              hipStream_t stream)
{
    const float* x      = (const float*)d_in[0];
    const int*   up_row = (const int*)  d_in[1];
    const int*   up_col = (const int*)  d_in[2];
    const float* up_val = (const float*)d_in[3];
    const int*   e_src  = (const int*)  d_in[4];
    const int*   e_dst  = (const int*)  d_in[5];
    const float* adjv   = (const float*)d_in[6];
    const float* W_res  = (const float*)d_in[7];
    const float* b_res  = (const float*)d_in[8];
    const float* bn0_g  = (const float*)d_in[9];
    const float* bn0_b  = (const float*)d_in[10];
    const float* bn1_g  = (const float*)d_in[11];
    const float* bn1_b  = (const float*)d_in[12];
    const float* Ui0_W  = (const float*)d_in[13];
    const float* Ui0_b  = (const float*)d_in[14];
    const float* Uj0_W  = (const float*)d_in[15];
    const float* Uj0_b  = (const float*)d_in[16];
    const float* Ui1_W  = (const float*)d_in[17];
    const float* Ui1_b  = (const float*)d_in[18];
    const float* Uj1_W  = (const float*)d_in[19];
    const float* Uj1_b  = (const float*)d_in[20];

    float* out = (float*)d_out;

    // ---- workspace layout ----
    char* ws = (char*)d_ws;
    size_t off = 0;
    auto alloc = [&](size_t bytes) -> char* {
        char* p = ws + off;
        off = (off + bytes + 255) & ~(size_t)255;
        return p;
    };
    ushort* XW    = (ushort*)alloc((size_t)V_PREV * F_OUT * 2);   // 8.4 MB
    ushort* XNJ   = (ushort*)alloc((size_t)V_PREV * F_OUT * 2);   // 8.4 MB
    ushort* XNI   = (ushort*)alloc((size_t)V_PREV * F_OUT * 2);   // 8.4 MB
    ushort* X1    = (ushort*)alloc((size_t)V_NEXT * F_OUT * 2);   // 33.6 MB
    // --- zeroed region (one memset): cnt, sumA, psum1s, psq1s ---
    int*    cnt   = (int*)   alloc(V_NEXT * 4);                   // 256 KB
    float*  sumA  = (float*) alloc(V_NEXT * 4);                   // 256 KB
    float*  psum1s= (float*) alloc(64 * 256 * 4);                 // 64 KB
    float*  psq1s = (float*) alloc(64 * 256 * 4);                 // 64 KB
    int*    offs  = (int*)   alloc(V_NEXT * 4);
    int*    cursor= (int*)   alloc(V_NEXT * 4);
    int*    bsum  = (int*)   alloc(256 * 4);
    int*    boff  = (int*)   alloc(256 * 4);
    int*    srcsA = (int*)   alloc((size_t)N_EDGE * 4);
    float*  valsA = (float*) alloc((size_t)N_EDGE * 4);
    int*    srcs0 = (int*)   alloc((size_t)N_EDGE * 4);
    float*  vals0 = (float*) alloc((size_t)N_EDGE * 4);
    int*    colof = (int*)   alloc(V_NEXT * 4);
    float*  valof = (float*) alloc(V_NEXT * 4);
    ushort* WresT = (ushort*)alloc(256 * 512 * 2);
    ushort* W0t   = (ushort*)alloc(512 * 512 * 2);
    ushort* W1cat = (ushort*)alloc(256 * 512 * 2);
    float*  biasUi= (float*) alloc(256 * 4);
    float*  psum0 = (float*) alloc(128 * 512 * 4);
    float*  psq0  = (float*) alloc(128 * 512 * 4);
    float*  sc0   = (float*) alloc(512 * 4);
    float*  sh0   = (float*) alloc(512 * 4);
    float*  sc1   = (float*) alloc(256 * 4);
    float*  sh1   = (float*) alloc(256 * 4);
    (void)ws_size; (void)in_sizes; (void)n_in; (void)out_size;

    // ---- prep + CSR build (independent of x) ----
    prep_weights_kernel<<<1024, 256, 0, stream>>>(W_res, Ui0_W, Uj0_W, Ui1_W, Uj1_W,
                                                  Ui1_b, b_res,
                                                  WresT, W0t, W1cat, biasUi);
    invert_up_kernel<<<NNZ_UP / 256, 256, 0, stream>>>(up_row, up_col, up_val, colof, valof);
    // one memset covers cnt + sumA + psum1s + psq1s (contiguous, 256-aligned sizes)
    hipMemsetAsync(cnt, 0, (size_t)V_NEXT * 8 + 64 * 256 * 8, stream);
    hist_kernel<<<N_EDGE / 256, 256, 0, stream>>>(e_dst, adjv, cnt, sumA);
    scan_block_kernel<<<256, 256, 0, stream>>>(cnt, offs, bsum);
    scan_top_kernel<<<1, 256, 0, stream>>>(bsum, boff);
    add_offs_kernel<<<256, 256, 0, stream>>>(offs, boff, cursor);
    fill_kernel<<<N_EDGE / 256, 256, 0, stream>>>(e_src, e_dst, adjv, colof, valof,
                                                  cursor, srcsA, valsA, srcs0, vals0);

    // ---- bn0 stats ----
    bn0_part_kernel<<<128, 256, 0, stream>>>(x, psum0, psq0);
    bn_finish_kernel<<<128, 256, 0, stream>>>(psum0, psq0, 128, 512, 1.0f / V_PREV,
                                              bn0_g, bn0_b, sc0, sh0);

    // ---- GEMM0 (fused bn0+relu+cast, XCD-grouped): XW, XNJ, XNI ----
    gemm0_fused_kernel<<<768, 256, 0, stream>>>(x, WresT, W0t, sc0, sh0, XW, XNJ, XNI);

    // ---- ECC layer 0 aggregation + bn1 partial stats ----
    gather0_kernel<<<V_NEXT / 4, 256, 0, stream>>>(offs, cnt, srcs0, vals0,
                                                   colof, valof, sumA,
                                                   XNJ, XNI, Ui0_b, Uj0_b, X1,
                                                   psum1s, psq1s);

    // ---- bn1 finish (64 slabs) ----
    bn_finish_kernel<<<64, 256, 0, stream>>>(psum1s, psq1s, 64, 256, 1.0f / V_NEXT,
                                             bn1_g, bn1_b, sc1, sh1);

    // ---- fused: gather G (LDS) + final GEMM + epilogue -> out ----
    gemm_final_fused_kernel<<<1024, 512, 0, stream>>>(X1, W1cat, sc1, sh1,
                                                      biasUi, Uj1_b, sumA,
                                                      offs, cnt, srcsA, valsA,
                                                      colof, valof, XW, out);
}

// Round 9
// 291.792 us; speedup vs baseline: 1.1431x; 1.1431x over previous
//
#include <hip/hip_runtime.h>

// ---------------------------------------------------------------------------
// Problem constants
// ---------------------------------------------------------------------------
#define V_PREV 16384
#define V_NEXT 65536
#define F_IN   512
#define F_OUT  256
#define NNZ_UP 65536
#define N_EDGE 524288

using f32x4 = __attribute__((ext_vector_type(4))) float;
using bfrag = __attribute__((ext_vector_type(8))) short;   // 8 x bf16

__device__ __forceinline__ ushort f2bf(float f) {
    union { float f; unsigned u; } v; v.f = f;
    unsigned r = (v.u + 0x7FFFu + ((v.u >> 16) & 1u)) >> 16;
    return (ushort)r;
}
__device__ __forceinline__ float bf2f(ushort h) {
    union { unsigned u; float f; } v; v.u = ((unsigned)h) << 16; return v.f;
}

// ---------------------------------------------------------------------------
// Weight prep:
//   WresT [256][512] = W_res^T
//   W0t   [512][512] = [Uj0 | Ui0]^T
//   W1cat [256][512] : k<256 -> Ui1^T, k>=256 -> Uj1^T   (for [H1|G] @ .)
//   biasUi[256] = Ui1_b + b_res
// ---------------------------------------------------------------------------
__global__ void prep_weights_kernel(const float* __restrict__ Wres,
                                    const float* __restrict__ Ui0W, const float* __restrict__ Uj0W,
                                    const float* __restrict__ Ui1W, const float* __restrict__ Uj1W,
                                    const float* __restrict__ Ui1b, const float* __restrict__ bres,
                                    ushort* __restrict__ WresT, ushort* __restrict__ W0t,
                                    ushort* __restrict__ W1cat, float* __restrict__ biasUi)
{
    int i = blockIdx.x * blockDim.x + threadIdx.x;   // 0 .. 512*512-1
    if (i < 256 * 512) {
        int n = i / 512, k = i % 512;
        WresT[i] = f2bf(Wres[k * 256 + n]);
        W1cat[i] = f2bf(k < 256 ? Ui1W[k * 256 + n] : Uj1W[(k - 256) * 256 + n]);
    }
    if (i < 512 * 512) {
        int n = i / 512, k = i % 512;
        W0t[i] = f2bf(n < 256 ? Uj0W[k * 256 + n] : Ui0W[k * 256 + (n - 256)]);
    }
    if (i < 256) biasUi[i] = Ui1b[i] + bres[i];
}

// ---------------------------------------------------------------------------
// Up-map invert + CSR build
// ---------------------------------------------------------------------------
__global__ void invert_up_kernel(const int* __restrict__ up_row, const int* __restrict__ up_col,
                                 const float* __restrict__ up_val,
                                 int* __restrict__ colof, float* __restrict__ valof)
{
    int k = blockIdx.x * blockDim.x + threadIdx.x;
    int r = up_row[k];
    colof[r] = up_col[k];
    valof[r] = up_val[k];
}

__global__ void hist_kernel(const int* __restrict__ dst, const float* __restrict__ adjv,
                            int* __restrict__ cnt, float* __restrict__ sumA)
{
    int e = blockIdx.x * blockDim.x + threadIdx.x;
    int d = dst[e];
    atomicAdd(&cnt[d], 1);
    atomicAdd(&sumA[d], adjv[e]);
}

__global__ void scan_block_kernel(const int* __restrict__ cnt, int* __restrict__ offs,
                                  int* __restrict__ bsum)
{
    __shared__ int buf[2][256];
    int t = threadIdx.x;
    int i = blockIdx.x * 256 + t;
    int v = cnt[i];
    int p = 0;
    buf[0][t] = v;
    __syncthreads();
    for (int d = 1; d < 256; d <<= 1) {
        int nv = buf[p][t] + ((t >= d) ? buf[p][t - d] : 0);
        buf[p ^ 1][t] = nv;
        p ^= 1;
        __syncthreads();
    }
    int incl = buf[p][t];
    offs[i] = incl - v;
    if (t == 255) bsum[blockIdx.x] = incl;
}

// merged scan_top + add_offs: every block scans bsum in LDS (redundant, tiny)
__global__ void add_offs2_kernel(int* __restrict__ offs, const int* __restrict__ bsum,
                                 int* __restrict__ cursor)
{
    __shared__ int buf[2][256];
    int t = threadIdx.x;
    int v = bsum[t];
    int p = 0;
    buf[0][t] = v;
    __syncthreads();
    for (int d = 1; d < 256; d <<= 1) {
        int nv = buf[p][t] + ((t >= d) ? buf[p][t - d] : 0);
        buf[p ^ 1][t] = nv;
        p ^= 1;
        __syncthreads();
    }
    int b = blockIdx.x;
    int excl = buf[p][b] - bsum[b];    // sum of bsum[0..b)
    int i = b * 256 + t;
    int o = offs[i] + excl;
    offs[i] = o;
    cursor[i] = o;
}

// dst-sorted edges; layer-0 variant pre-composes the up map
__global__ void fill_kernel(const int* __restrict__ src, const int* __restrict__ dst,
                            const float* __restrict__ adjv,
                            const int* __restrict__ colof, const float* __restrict__ valof,
                            int* __restrict__ cursor,
                            int* __restrict__ srcsA, float* __restrict__ valsA,
                            int* __restrict__ srcs0, float* __restrict__ vals0)
{
    int e = blockIdx.x * blockDim.x + threadIdx.x;
    int d = dst[e];
    int s = src[e];
    float a = adjv[e];
    int p = atomicAdd(&cursor[d], 1);
    srcsA[p] = s;
    valsA[p] = a;
    srcs0[p] = colof[s];
    vals0[p] = a * valof[s];
}

// ---------------------------------------------------------------------------
// BatchNorm stats (bn0)
// ---------------------------------------------------------------------------
__global__ void bn0_part_kernel(const float* __restrict__ x,
                                float* __restrict__ psum, float* __restrict__ psq)
{
    int blk = blockIdx.x, t = threadIdx.x;
    float s0 = 0, s1 = 0, q0 = 0, q1 = 0;
    for (int r = 0; r < 128; r++) {
        size_t base = ((size_t)blk * 128 + r) * 512;
        float a = x[base + t], b = x[base + t + 256];
        s0 += a; q0 += a * a; s1 += b; q1 += b * b;
    }
    psum[blk * 512 + t] = s0; psum[blk * 512 + t + 256] = s1;
    psq [blk * 512 + t] = q0; psq [blk * 512 + t + 256] = q1;
}

// Parallel finish: one wave per channel; produces sc = g*rstd, sh = b - mean*sc
__global__ void bn_finish_kernel(const float* __restrict__ psum, const float* __restrict__ psq,
                                 int nblocks, int C, float invN,
                                 const float* __restrict__ g, const float* __restrict__ b,
                                 float* __restrict__ sc, float* __restrict__ sh)
{
    int gw = (blockIdx.x * blockDim.x + threadIdx.x) >> 6;   // channel
    int lane = threadIdx.x & 63;
    if (gw >= C) return;
    float s = 0, q = 0;
    for (int i = lane; i < nblocks; i += 64) {
        s += psum[(size_t)i * C + gw];
        q += psq [(size_t)i * C + gw];
    }
#pragma unroll
    for (int d = 32; d > 0; d >>= 1) {
        s += __shfl_xor(s, d);
        q += __shfl_xor(q, d);
    }
    if (lane == 0) {
        float m = s * invN;
        float v = q * invN - m * m;
        float r = rsqrtf(v + 1e-5f);
        float scale = r * g[gw];
        sc[gw] = scale;
        sh[gw] = b[gw] - m * scale;
    }
}

// ---------------------------------------------------------------------------
// GEMM0 fused: reads x f32 [16384,512] directly. 1D grid 768, XCD-grouped.
//   bx 0,1: XW  = bf16(x) @ WresT^T
//   bx 2,3: XNJ = relu(bn0(x)) @ Uj0
//   bx 4,5: XNI = relu(bn0(x)) @ Ui0
// LDS linear [row][32] + XOR unit^(row&3): conflict-free write+read.
// ---------------------------------------------------------------------------
__global__ __launch_bounds__(256)
void gemm0_fused_kernel(const float* __restrict__ x,
                        const ushort* __restrict__ WresT, const ushort* __restrict__ W0t,
                        const float* __restrict__ sc0, const float* __restrict__ sh0,
                        ushort* __restrict__ XW, ushort* __restrict__ XNJ,
                        ushort* __restrict__ XNI)
{
    __shared__ ushort As[128 * 32];
    __shared__ ushort Bs[128 * 32];
    __shared__ float s_sc[512], s_sh[512];

    const int tid = threadIdx.x;
    const int id   = blockIdx.x;
    const int xcd  = id & 7;
    const int rest = id >> 3;
    const int slot = rest / 6;
    const int bx   = rest - slot * 6;
    const int by   = slot * 8 + xcd;

    const bool bnmode = bx >= 2;
    const ushort* Bt = bnmode ? W0t : WresT;
    const int btrow = bnmode ? (bx - 2) * 128 : bx * 128;
    ushort* Cout = (bx < 2) ? XW : (bx < 4 ? XNJ : XNI);
    const int colbase = (bx & 1) * 128;
    const int tM = by * 128;

    for (int i = tid; i < 512; i += 256) { s_sc[i] = sc0[i]; s_sh[i] = sh0[i]; }
    __syncthreads();

    const int lane = tid & 63;
    const int wave = tid >> 6;
    const int wm = wave >> 1, wn = wave & 1;
    const int lr = lane & 15, lg = lane >> 4;

    const int ra = tid >> 1;
    const int ua = (tid & 1) * 2;
    const int rb = tid >> 2;
    const int ub = tid & 3;

    f32x4 acc[4][4] = {};

    for (int k0 = 0; k0 < 512; k0 += 32) {
        const float* xp = &x[(size_t)(tM + ra) * 512 + k0 + ua * 8];
        float4 f0 = *(const float4*)(xp);
        float4 f1 = *(const float4*)(xp + 4);
        float4 f2 = *(const float4*)(xp + 8);
        float4 f3 = *(const float4*)(xp + 12);
        float vv[16] = { f0.x,f0.y,f0.z,f0.w, f1.x,f1.y,f1.z,f1.w,
                         f2.x,f2.y,f2.z,f2.w, f3.x,f3.y,f3.z,f3.w };
        ushort hh[16];
        if (bnmode) {
#pragma unroll
            for (int j = 0; j < 16; j++) {
                int c = k0 + ua * 8 + j;
                hh[j] = f2bf(fmaxf(vv[j] * s_sc[c] + s_sh[c], 0.0f));
            }
        } else {
#pragma unroll
            for (int j = 0; j < 16; j++) hh[j] = f2bf(vv[j]);
        }
        *(uint4*)&As[ra * 32 + ((ua    ) ^ (ra & 3)) * 8] = *(uint4*)&hh[0];
        *(uint4*)&As[ra * 32 + ((ua + 1) ^ (ra & 3)) * 8] = *(uint4*)&hh[8];

#pragma unroll
        for (int i = 0; i < 2; i++) {
            int row = rb + i * 64;
            *(uint4*)&Bs[row * 32 + (ub ^ (row & 3)) * 8] =
                *(const uint4*)&Bt[(size_t)(btrow + row) * 512 + k0 + ub * 8];
        }
        __syncthreads();

        bfrag af[4], bfv[4];
#pragma unroll
        for (int mm = 0; mm < 4; mm++) {
            int row = wm * 64 + mm * 16 + lr;
            af[mm] = *(const bfrag*)&As[row * 32 + (lg ^ (row & 3)) * 8];
        }
#pragma unroll
        for (int nn = 0; nn < 4; nn++) {
            int row = wn * 64 + nn * 16 + lr;
            bfv[nn] = *(const bfrag*)&Bs[row * 32 + (lg ^ (row & 3)) * 8];
        }
#pragma unroll
        for (int mm = 0; mm < 4; mm++)
#pragma unroll
            for (int nn = 0; nn < 4; nn++)
                acc[mm][nn] = __builtin_amdgcn_mfma_f32_16x16x32_bf16(af[mm], bfv[nn], acc[mm][nn], 0, 0, 0);
        __syncthreads();
    }

#pragma unroll
    for (int mm = 0; mm < 4; mm++)
#pragma unroll
        for (int nn = 0; nn < 4; nn++)
#pragma unroll
            for (int r = 0; r < 4; r++) {
                int row = tM + wm * 64 + mm * 16 + lg * 4 + r;
                int col = colbase + wn * 64 + nn * 16 + lr;
                Cout[(size_t)row * 256 + col] = f2bf(acc[mm][nn][r]);
            }
}

// ---------------------------------------------------------------------------
// Gather layer 0 + fused bn1 partial stats. 4-wide batched row loads (MLP=4).
//   X1[d] = ui0_b + valof[d]*XNI[colof[d]] + sumA[d]*uj0_b + sum vals0*XNJ[srcs0]
// ---------------------------------------------------------------------------
__global__ __launch_bounds__(256)
void gather0_kernel(const int* __restrict__ offs, const int* __restrict__ cnt,
                    const int* __restrict__ srcs0, const float* __restrict__ vals0,
                    const int* __restrict__ colof, const float* __restrict__ valof,
                    const float* __restrict__ sumA,
                    const ushort* __restrict__ XNJ, const ushort* __restrict__ XNI,
                    const float* __restrict__ ui_b, const float* __restrict__ uj_b,
                    ushort* __restrict__ X1,
                    float* __restrict__ psum1s, float* __restrict__ psq1s)
{
    __shared__ float redS[4][256];
    __shared__ float redQ[4][256];

    int wave = threadIdx.x >> 6;
    int d = blockIdx.x * 4 + wave;
    int f = (threadIdx.x & 63) * 4;
    int c = colof[d];
    float s = valof[d];
    float sA = sumA[d];
    ushort4 u = *(const ushort4*)&XNI[(size_t)c * 256 + f];
    const ushort* up = (const ushort*)&u;
    float a0 = ui_b[f + 0] + sA * uj_b[f + 0] + s * bf2f(up[0]);
    float a1 = ui_b[f + 1] + sA * uj_b[f + 1] + s * bf2f(up[1]);
    float a2 = ui_b[f + 2] + sA * uj_b[f + 2] + s * bf2f(up[2]);
    float a3 = ui_b[f + 3] + sA * uj_b[f + 3] + s * bf2f(up[3]);

    int st = offs[d], n = cnt[d];
    for (int e0 = 0; e0 < n; e0 += 4) {
        int   i0 = srcs0[st + e0];
        float w0 = vals0[st + e0];
        int i1 = 0, i2 = 0, i3 = 0;
        float w1 = 0, w2 = 0, w3 = 0;
        if (e0 + 1 < n) { i1 = srcs0[st + e0 + 1]; w1 = vals0[st + e0 + 1]; }
        if (e0 + 2 < n) { i2 = srcs0[st + e0 + 2]; w2 = vals0[st + e0 + 2]; }
        if (e0 + 3 < n) { i3 = srcs0[st + e0 + 3]; w3 = vals0[st + e0 + 3]; }
        ushort4 v0 = *(const ushort4*)&XNJ[(size_t)i0 * 256 + f];
        ushort4 v1 = *(const ushort4*)&XNJ[(size_t)i1 * 256 + f];
        ushort4 v2 = *(const ushort4*)&XNJ[(size_t)i2 * 256 + f];
        ushort4 v3 = *(const ushort4*)&XNJ[(size_t)i3 * 256 + f];
        const ushort* p0 = (const ushort*)&v0;
        const ushort* p1 = (const ushort*)&v1;
        const ushort* p2 = (const ushort*)&v2;
        const ushort* p3 = (const ushort*)&v3;
        a0 += w0 * bf2f(p0[0]) + w1 * bf2f(p1[0]) + w2 * bf2f(p2[0]) + w3 * bf2f(p3[0]);
        a1 += w0 * bf2f(p0[1]) + w1 * bf2f(p1[1]) + w2 * bf2f(p2[1]) + w3 * bf2f(p3[1]);
        a2 += w0 * bf2f(p0[2]) + w1 * bf2f(p1[2]) + w2 * bf2f(p2[2]) + w3 * bf2f(p3[2]);
        a3 += w0 * bf2f(p0[3]) + w1 * bf2f(p1[3]) + w2 * bf2f(p2[3]) + w3 * bf2f(p3[3]);
    }
    *(ushort4*)&X1[(size_t)d * 256 + f] =
        make_ushort4(f2bf(a0), f2bf(a1), f2bf(a2), f2bf(a3));

    // bn1 partial stats: block-reduce then 2 atomics per thread into 64 slabs
    redS[wave][f + 0] = a0; redS[wave][f + 1] = a1;
    redS[wave][f + 2] = a2; redS[wave][f + 3] = a3;
    redQ[wave][f + 0] = a0 * a0; redQ[wave][f + 1] = a1 * a1;
    redQ[wave][f + 2] = a2 * a2; redQ[wave][f + 3] = a3 * a3;
    __syncthreads();
    int t = threadIdx.x;   // channel
    float ssum = redS[0][t] + redS[1][t] + redS[2][t] + redS[3][t];
    float sq   = redQ[0][t] + redQ[1][t] + redQ[2][t] + redQ[3][t];
    int slab = (blockIdx.x & 63) * 256 + t;
    atomicAdd(&psum1s[slab], ssum);
    atomicAdd(&psq1s[slab], sq);
}

// ---------------------------------------------------------------------------
// Gather layer 1 (pre-GEMM, bn1+relu folded), 4-wide batched row loads:
//   G[d] = sum_e valsA * relu(sc1*X1[srcsA] + sh1)     (bf16 out)
// ---------------------------------------------------------------------------
__global__ __launch_bounds__(256)
void gather1G_kernel(const int* __restrict__ offs, const int* __restrict__ cnt,
                     const int* __restrict__ srcsA, const float* __restrict__ valsA,
                     const ushort* __restrict__ X1,
                     const float* __restrict__ sc1, const float* __restrict__ sh1,
                     ushort* __restrict__ G)
{
    int d = blockIdx.x * 4 + (threadIdx.x >> 6);
    int f = (threadIdx.x & 63) * 4;
    float4 sc = *(const float4*)&sc1[f];
    float4 sh = *(const float4*)&sh1[f];
    float a0 = 0, a1 = 0, a2 = 0, a3 = 0;

    int st = offs[d], n = cnt[d];
    for (int e0 = 0; e0 < n; e0 += 4) {
        int   i0 = srcsA[st + e0];
        float w0 = valsA[st + e0];
        int i1 = 0, i2 = 0, i3 = 0;
        float w1 = 0, w2 = 0, w3 = 0;
        if (e0 + 1 < n) { i1 = srcsA[st + e0 + 1]; w1 = valsA[st + e0 + 1]; }
        if (e0 + 2 < n) { i2 = srcsA[st + e0 + 2]; w2 = valsA[st + e0 + 2]; }
        if (e0 + 3 < n) { i3 = srcsA[st + e0 + 3]; w3 = valsA[st + e0 + 3]; }
        ushort4 v0 = *(const ushort4*)&X1[(size_t)i0 * 256 + f];
        ushort4 v1 = *(const ushort4*)&X1[(size_t)i1 * 256 + f];
        ushort4 v2 = *(const ushort4*)&X1[(size_t)i2 * 256 + f];
        ushort4 v3 = *(const ushort4*)&X1[(size_t)i3 * 256 + f];
        const ushort* p0 = (const ushort*)&v0;
        const ushort* p1 = (const ushort*)&v1;
        const ushort* p2 = (const ushort*)&v2;
        const ushort* p3 = (const ushort*)&v3;
        a0 += w0 * fmaxf(bf2f(p0[0]) * sc.x + sh.x, 0.0f)
            + w1 * fmaxf(bf2f(p1[0]) * sc.x + sh.x, 0.0f)
            + w2 * fmaxf(bf2f(p2[0]) * sc.x + sh.x, 0.0f)
            + w3 * fmaxf(bf2f(p3[0]) * sc.x + sh.x, 0.0f);
        a1 += w0 * fmaxf(bf2f(p0[1]) * sc.y + sh.y, 0.0f)
            + w1 * fmaxf(bf2f(p1[1]) * sc.y + sh.y, 0.0f)
            + w2 * fmaxf(bf2f(p2[1]) * sc.y + sh.y, 0.0f)
            + w3 * fmaxf(bf2f(p3[1]) * sc.y + sh.y, 0.0f);
        a2 += w0 * fmaxf(bf2f(p0[2]) * sc.z + sh.z, 0.0f)
            + w1 * fmaxf(bf2f(p1[2]) * sc.z + sh.z, 0.0f)
            + w2 * fmaxf(bf2f(p2[2]) * sc.z + sh.z, 0.0f)
            + w3 * fmaxf(bf2f(p3[2]) * sc.z + sh.z, 0.0f);
        a3 += w0 * fmaxf(bf2f(p0[3]) * sc.w + sh.w, 0.0f)
            + w1 * fmaxf(bf2f(p1[3]) * sc.w + sh.w, 0.0f)
            + w2 * fmaxf(bf2f(p2[3]) * sc.w + sh.w, 0.0f)
            + w3 * fmaxf(bf2f(p3[3]) * sc.w + sh.w, 0.0f);
    }
    *(ushort4*)&G[(size_t)d * 256 + f] =
        make_ushort4(f2bf(a0), f2bf(a1), f2bf(a2), f2bf(a3));
}

// ---------------------------------------------------------------------------
// GEMM final: out[65536,256] f32 = [relu(bn1(X1)) | G] @ W1cat^T + biases + res
// grid 512 x 256thr; 128 M-rows x 256 N per block; BK=32; LDS 26KB.
// ---------------------------------------------------------------------------
__global__ __launch_bounds__(256, 2)
void gemm_final_kernel(const ushort* __restrict__ X1, const ushort* __restrict__ G,
                       const ushort* __restrict__ W1cat,
                       const float* __restrict__ sc1, const float* __restrict__ sh1,
                       const float* __restrict__ biasUi, const float* __restrict__ uj1_b,
                       const float* __restrict__ sumA,
                       const int* __restrict__ colof, const float* __restrict__ valof,
                       const ushort* __restrict__ XW,
                       float* __restrict__ out)
{
    __shared__ ushort As[128 * 32];
    __shared__ ushort Bs[256 * 32];
    __shared__ float s_sc[256], s_sh[256];

    const int tid = threadIdx.x;
    const int tM = blockIdx.x * 128;

    s_sc[tid] = sc1[tid]; s_sh[tid] = sh1[tid];
    __syncthreads();

    const int lane = tid & 63;
    const int wave = tid >> 6;
    const int wm = wave >> 1, wn = wave & 1;    // wave tile 64 rows x 128 cols
    const int lr = lane & 15, lg = lane >> 4;

    const int rstg = tid >> 2;      // 0..63
    const int ustg = tid & 3;

    f32x4 acc[4][8] = {};

    for (int k0 = 0; k0 < 512; k0 += 32) {
        // --- A stage: 128 rows x 4 units, 2 per thread ---
#pragma unroll
        for (int i = 0; i < 2; i++) {
            int row = rstg + i * 64;
            ushort h[8];
            if (k0 < 256) {
                *(uint4*)h = *(const uint4*)&X1[(size_t)(tM + row) * 256 + k0 + ustg * 8];
#pragma unroll
                for (int j = 0; j < 8; j++) {
                    int c = k0 + ustg * 8 + j;
                    h[j] = f2bf(fmaxf(bf2f(h[j]) * s_sc[c] + s_sh[c], 0.0f));
                }
            } else {
                *(uint4*)h = *(const uint4*)&G[(size_t)(tM + row) * 256 + (k0 - 256) + ustg * 8];
            }
            *(uint4*)&As[row * 32 + (ustg ^ (row & 3)) * 8] = *(uint4*)h;
        }
        // --- B stage: 256 rows x 4 units, 4 per thread ---
#pragma unroll
        for (int i = 0; i < 4; i++) {
            int row = rstg + i * 64;
            *(uint4*)&Bs[row * 32 + (ustg ^ (row & 3)) * 8] =
                *(const uint4*)&W1cat[(size_t)row * 512 + k0 + ustg * 8];
        }
        __syncthreads();

        bfrag af[4], bfv[8];
#pragma unroll
        for (int mm = 0; mm < 4; mm++) {
            int row = wm * 64 + mm * 16 + lr;
            af[mm] = *(const bfrag*)&As[row * 32 + (lg ^ (row & 3)) * 8];
        }
#pragma unroll
        for (int nn = 0; nn < 8; nn++) {
            int row = wn * 128 + nn * 16 + lr;
            bfv[nn] = *(const bfrag*)&Bs[row * 32 + (lg ^ (row & 3)) * 8];
        }
#pragma unroll
        for (int mm = 0; mm < 4; mm++)
#pragma unroll
            for (int nn = 0; nn < 8; nn++)
                acc[mm][nn] = __builtin_amdgcn_mfma_f32_16x16x32_bf16(af[mm], bfv[nn], acc[mm][nn], 0, 0, 0);
        __syncthreads();
    }

    // epilogue
    float bUi[8], bUj[8];
#pragma unroll
    for (int nn = 0; nn < 8; nn++) {
        int col = wn * 128 + nn * 16 + lr;
        bUi[nn] = biasUi[col];
        bUj[nn] = uj1_b[col];
    }
#pragma unroll
    for (int mm = 0; mm < 4; mm++) {
#pragma unroll
        for (int r = 0; r < 4; r++) {
            int row = tM + wm * 64 + mm * 16 + lg * 4 + r;
            int c = colof[row];
            float s = valof[row];
            float sA = sumA[row];
#pragma unroll
            for (int nn = 0; nn < 8; nn++) {
                int col = wn * 128 + nn * 16 + lr;
                float v = acc[mm][nn][r] + bUi[nn] + sA * bUj[nn]
                        + s * bf2f(XW[(size_t)c * 256 + col]);
                out[(size_t)row * 256 + col] = v;
            }
        }
    }
}

// ---------------------------------------------------------------------------
// Host launcher
// ---------------------------------------------------------------------------
extern "C" void kernel_launch(void* const* d_in, const int* in_sizes, int n_in,
                              void* d_out, int out_size, void* d_ws, size_t ws_size,
                              hipStream_t stream)
{
    const float* x      = (const float*)d_in[0];
    const int*   up_row = (const int*)  d_in[1];
    const int*   up_col = (const int*)  d_in[2];
    const float* up_val = (const float*)d_in[3];
    const int*   e_src  = (const int*)  d_in[4];
    const int*   e_dst  = (const int*)  d_in[5];
    const float* adjv   = (const float*)d_in[6];
    const float* W_res  = (const float*)d_in[7];
    const float* b_res  = (const float*)d_in[8];
    const float* bn0_g  = (const float*)d_in[9];
    const float* bn0_b  = (const float*)d_in[10];
    const float* bn1_g  = (const float*)d_in[11];
    const float* bn1_b  = (const float*)d_in[12];
    const float* Ui0_W  = (const float*)d_in[13];
    const float* Ui0_b  = (const float*)d_in[14];
    const float* Uj0_W  = (const float*)d_in[15];
    const float* Uj0_b  = (const float*)d_in[16];
    const float* Ui1_W  = (const float*)d_in[17];
    const float* Ui1_b  = (const float*)d_in[18];
    const float* Uj1_W  = (const float*)d_in[19];
    const float* Uj1_b  = (const float*)d_in[20];

    float* out = (float*)d_out;

    // ---- workspace layout ----
    char* ws = (char*)d_ws;
    size_t off = 0;
    auto alloc = [&](size_t bytes) -> char* {
        char* p = ws + off;
        off = (off + bytes + 255) & ~(size_t)255;
        return p;
    };
    ushort* XW    = (ushort*)alloc((size_t)V_PREV * F_OUT * 2);   // 8.4 MB
    ushort* XNJ   = (ushort*)alloc((size_t)V_PREV * F_OUT * 2);   // 8.4 MB
    ushort* XNI   = (ushort*)alloc((size_t)V_PREV * F_OUT * 2);   // 8.4 MB
    ushort* X1    = (ushort*)alloc((size_t)V_NEXT * F_OUT * 2);   // 33.6 MB
    ushort* G     = (ushort*)alloc((size_t)V_NEXT * F_OUT * 2);   // 33.6 MB
    // --- zeroed region (one memset): cnt, sumA, psum1s, psq1s ---
    int*    cnt   = (int*)   alloc(V_NEXT * 4);                   // 256 KB
    float*  sumA  = (float*) alloc(V_NEXT * 4);                   // 256 KB
    float*  psum1s= (float*) alloc(64 * 256 * 4);                 // 64 KB
    float*  psq1s = (float*) alloc(64 * 256 * 4);                 // 64 KB
    int*    offs  = (int*)   alloc(V_NEXT * 4);
    int*    cursor= (int*)   alloc(V_NEXT * 4);
    int*    bsum  = (int*)   alloc(256 * 4);
    int*    srcsA = (int*)   alloc((size_t)N_EDGE * 4);
    float*  valsA = (float*) alloc((size_t)N_EDGE * 4);
    int*    srcs0 = (int*)   alloc((size_t)N_EDGE * 4);
    float*  vals0 = (float*) alloc((size_t)N_EDGE * 4);
    int*    colof = (int*)   alloc(V_NEXT * 4);
    float*  valof = (float*) alloc(V_NEXT * 4);
    ushort* WresT = (ushort*)alloc(256 * 512 * 2);
    ushort* W0t   = (ushort*)alloc(512 * 512 * 2);
    ushort* W1cat = (ushort*)alloc(256 * 512 * 2);
    float*  biasUi= (float*) alloc(256 * 4);
    float*  psum0 = (float*) alloc(128 * 512 * 4);
    float*  psq0  = (float*) alloc(128 * 512 * 4);
    float*  sc0   = (float*) alloc(512 * 4);
    float*  sh0   = (float*) alloc(512 * 4);
    float*  sc1   = (float*) alloc(256 * 4);
    float*  sh1   = (float*) alloc(256 * 4);
    (void)ws_size; (void)in_sizes; (void)n_in; (void)out_size;

    // ---- prep + CSR build (independent of x) ----
    prep_weights_kernel<<<1024, 256, 0, stream>>>(W_res, Ui0_W, Uj0_W, Ui1_W, Uj1_W,
                                                  Ui1_b, b_res,
                                                  WresT, W0t, W1cat, biasUi);
    invert_up_kernel<<<NNZ_UP / 256, 256, 0, stream>>>(up_row, up_col, up_val, colof, valof);
    // one memset covers cnt + sumA + psum1s + psq1s (contiguous allocations)
    hipMemsetAsync(cnt, 0, (size_t)V_NEXT * 8 + 64 * 256 * 8, stream);
    hist_kernel<<<N_EDGE / 256, 256, 0, stream>>>(e_dst, adjv, cnt, sumA);
    scan_block_kernel<<<256, 256, 0, stream>>>(cnt, offs, bsum);
    add_offs2_kernel<<<256, 256, 0, stream>>>(offs, bsum, cursor);
    fill_kernel<<<N_EDGE / 256, 256, 0, stream>>>(e_src, e_dst, adjv, colof, valof,
                                                  cursor, srcsA, valsA, srcs0, vals0);

    // ---- bn0 stats ----
    bn0_part_kernel<<<128, 256, 0, stream>>>(x, psum0, psq0);
    bn_finish_kernel<<<128, 256, 0, stream>>>(psum0, psq0, 128, 512, 1.0f / V_PREV,
                                              bn0_g, bn0_b, sc0, sh0);

    // ---- GEMM0 (fused bn0+relu+cast, XCD-grouped): XW, XNJ, XNI ----
    gemm0_fused_kernel<<<768, 256, 0, stream>>>(x, WresT, W0t, sc0, sh0, XW, XNJ, XNI);

    // ---- ECC layer 0 aggregation + bn1 partial stats ----
    gather0_kernel<<<V_NEXT / 4, 256, 0, stream>>>(offs, cnt, srcs0, vals0,
                                                   colof, valof, sumA,
                                                   XNJ, XNI, Ui0_b, Uj0_b, X1,
                                                   psum1s, psq1s);

    // ---- bn1 finish (64 slabs) ----
    bn_finish_kernel<<<64, 256, 0, stream>>>(psum1s, psq1s, 64, 256, 1.0f / V_NEXT,
                                             bn1_g, bn1_b, sc1, sh1);

    // ---- ECC layer 1 aggregation BEFORE the GEMM (commuted) ----
    gather1G_kernel<<<V_NEXT / 4, 256, 0, stream>>>(offs, cnt, srcsA, valsA,
                                                    X1, sc1, sh1, G);

    // ---- final GEMM: out = [H1|G] @ W1cat + biases + residual ----
    gemm_final_kernel<<<512, 256, 0, stream>>>(X1, G, W1cat, sc1, sh1,
                                               biasUi, Uj1_b, sumA,
                                               colof, valof, XW, out);
}

// Round 10
// 274.322 us; speedup vs baseline: 1.2159x; 1.0637x over previous
//
#include <hip/hip_runtime.h>

// ---------------------------------------------------------------------------
// Problem constants
// ---------------------------------------------------------------------------
#define V_PREV 16384
#define V_NEXT 65536
#define F_IN   512
#define F_OUT  256
#define NNZ_UP 65536
#define N_EDGE 524288

using f32x4 = __attribute__((ext_vector_type(4))) float;
using bfrag = __attribute__((ext_vector_type(8))) short;   // 8 x bf16

__device__ __forceinline__ ushort f2bf(float f) {
    union { float f; unsigned u; } v; v.f = f;
    unsigned r = (v.u + 0x7FFFu + ((v.u >> 16) & 1u)) >> 16;
    return (ushort)r;
}
__device__ __forceinline__ float bf2f(ushort h) {
    union { unsigned u; float f; } v; v.u = ((unsigned)h) << 16; return v.f;
}

// ---------------------------------------------------------------------------
// Fat kernel 1: prep_weights (blocks 0..1023) + invert_up (1024..1279)
//             + zero cnt/sumA/psum1s/psq1s (1280..1919)
// ---------------------------------------------------------------------------
__global__ void prep_all_kernel(const float* __restrict__ Wres,
                                const float* __restrict__ Ui0W, const float* __restrict__ Uj0W,
                                const float* __restrict__ Ui1W, const float* __restrict__ Uj1W,
                                const float* __restrict__ Ui1b, const float* __restrict__ bres,
                                const int* __restrict__ up_row, const int* __restrict__ up_col,
                                const float* __restrict__ up_val,
                                ushort* __restrict__ WresT, ushort* __restrict__ W0t,
                                ushort* __restrict__ W1cat, float* __restrict__ biasUi,
                                int* __restrict__ colof, float* __restrict__ valof,
                                int* __restrict__ zeroBase)
{
    int b = blockIdx.x, t = threadIdx.x;
    if (b < 1024) {
        int i = b * 256 + t;                      // 0 .. 262143
        if (i < 256 * 512) {
            int n = i / 512, k = i % 512;
            WresT[i] = f2bf(Wres[k * 256 + n]);
            W1cat[i] = f2bf(k < 256 ? Ui1W[k * 256 + n] : Uj1W[(k - 256) * 256 + n]);
        }
        {
            int n = i / 512, k = i % 512;
            W0t[i] = f2bf(n < 256 ? Uj0W[k * 256 + n] : Ui0W[k * 256 + (n - 256)]);
        }
        if (i < 256) biasUi[i] = Ui1b[i] + bres[i];
    } else if (b < 1280) {
        int k = (b - 1024) * 256 + t;             // 0 .. 65535
        int r = up_row[k];
        colof[r] = up_col[k];
        valof[r] = up_val[k];
    } else {
        int i = (b - 1280) * 256 + t;             // 0 .. 163839
        zeroBase[i] = 0;
    }
}

// ---------------------------------------------------------------------------
// Fat kernel 2: hist (blocks 0..2047) + bn0_part (2048..2175)
// ---------------------------------------------------------------------------
__global__ void hist_bn0_kernel(const int* __restrict__ dst, const float* __restrict__ adjv,
                                int* __restrict__ cnt, float* __restrict__ sumA,
                                const float* __restrict__ x,
                                float* __restrict__ psum0, float* __restrict__ psq0)
{
    int b = blockIdx.x, t = threadIdx.x;
    if (b < 2048) {
        int e = b * 256 + t;
        int d = dst[e];
        atomicAdd(&cnt[d], 1);
        atomicAdd(&sumA[d], adjv[e]);
    } else {
        int blk = b - 2048;                        // 0..127
        float s0 = 0, s1 = 0, q0 = 0, q1 = 0;
        for (int r = 0; r < 128; r++) {
            size_t base = ((size_t)blk * 128 + r) * 512;
            float a = x[base + t], bb = x[base + t + 256];
            s0 += a; q0 += a * a; s1 += bb; q1 += bb * bb;
        }
        psum0[blk * 512 + t] = s0; psum0[blk * 512 + t + 256] = s1;
        psq0 [blk * 512 + t] = q0; psq0 [blk * 512 + t + 256] = q1;
    }
}

// ---------------------------------------------------------------------------
// CSR scan
// ---------------------------------------------------------------------------
__global__ void scan_block_kernel(const int* __restrict__ cnt, int* __restrict__ offs,
                                  int* __restrict__ bsum)
{
    __shared__ int buf[2][256];
    int t = threadIdx.x;
    int i = blockIdx.x * 256 + t;
    int v = cnt[i];
    int p = 0;
    buf[0][t] = v;
    __syncthreads();
    for (int d = 1; d < 256; d <<= 1) {
        int nv = buf[p][t] + ((t >= d) ? buf[p][t - d] : 0);
        buf[p ^ 1][t] = nv;
        p ^= 1;
        __syncthreads();
    }
    int incl = buf[p][t];
    offs[i] = incl - v;
    if (t == 255) bsum[blockIdx.x] = incl;
}

// Fat kernel 3: add_offs2 (blocks 0..255) + bn0 finish (256..383)
__global__ void add_offs_bnfin_kernel(int* __restrict__ offs, const int* __restrict__ bsum,
                                      int* __restrict__ cursor,
                                      const float* __restrict__ psum0, const float* __restrict__ psq0,
                                      const float* __restrict__ g0, const float* __restrict__ b0,
                                      float* __restrict__ sc0, float* __restrict__ sh0)
{
    int b = blockIdx.x, t = threadIdx.x;
    if (b < 256) {
        __shared__ int buf[2][256];
        int v = bsum[t];
        int p = 0;
        buf[0][t] = v;
        __syncthreads();
        for (int d = 1; d < 256; d <<= 1) {
            int nv = buf[p][t] + ((t >= d) ? buf[p][t - d] : 0);
            buf[p ^ 1][t] = nv;
            p ^= 1;
            __syncthreads();
        }
        int excl = buf[p][b] - bsum[b];
        int i = b * 256 + t;
        int o = offs[i] + excl;
        offs[i] = o;
        cursor[i] = o;
    } else {
        int vb = b - 256;                          // 0..127
        int gw = (vb * 256 + t) >> 6;              // channel 0..511
        int lane = t & 63;
        float s = 0, q = 0;
        for (int i = lane; i < 128; i += 64) {
            s += psum0[(size_t)i * 512 + gw];
            q += psq0 [(size_t)i * 512 + gw];
        }
#pragma unroll
        for (int d = 32; d > 0; d >>= 1) {
            s += __shfl_xor(s, d);
            q += __shfl_xor(q, d);
        }
        if (lane == 0) {
            float m = s * (1.0f / V_PREV);
            float v = q * (1.0f / V_PREV) - m * m;
            float r = rsqrtf(v + 1e-5f);
            float scale = r * g0[gw];
            sc0[gw] = scale;
            sh0[gw] = b0[gw] - m * scale;
        }
    }
}

// dst-sorted edges; layer-0 variant pre-composes the up map
__global__ void fill_kernel(const int* __restrict__ src, const int* __restrict__ dst,
                            const float* __restrict__ adjv,
                            const int* __restrict__ colof, const float* __restrict__ valof,
                            int* __restrict__ cursor,
                            int* __restrict__ srcsA, float* __restrict__ valsA,
                            int* __restrict__ srcs0, float* __restrict__ vals0)
{
    int e = blockIdx.x * blockDim.x + threadIdx.x;
    int d = dst[e];
    int s = src[e];
    float a = adjv[e];
    int p = atomicAdd(&cursor[d], 1);
    srcsA[p] = s;
    valsA[p] = a;
    srcs0[p] = colof[s];
    vals0[p] = a * valof[s];
}

// bn1 finish (standalone)
__global__ void bn_finish_kernel(const float* __restrict__ psum, const float* __restrict__ psq,
                                 int nblocks, int C, float invN,
                                 const float* __restrict__ g, const float* __restrict__ b,
                                 float* __restrict__ sc, float* __restrict__ sh)
{
    int gw = (blockIdx.x * blockDim.x + threadIdx.x) >> 6;
    int lane = threadIdx.x & 63;
    if (gw >= C) return;
    float s = 0, q = 0;
    for (int i = lane; i < nblocks; i += 64) {
        s += psum[(size_t)i * C + gw];
        q += psq [(size_t)i * C + gw];
    }
#pragma unroll
    for (int d = 32; d > 0; d >>= 1) {
        s += __shfl_xor(s, d);
        q += __shfl_xor(q, d);
    }
    if (lane == 0) {
        float m = s * invN;
        float v = q * invN - m * m;
        float r = rsqrtf(v + 1e-5f);
        float scale = r * g[gw];
        sc[gw] = scale;
        sh[gw] = b[gw] - m * scale;
    }
}

// ---------------------------------------------------------------------------
// GEMM0 fused: reads x f32 [16384,512] directly. 1D grid 768, XCD-grouped.
//   bx 0,1: XW  = bf16(x) @ WresT^T
//   bx 2,3: XNJ = relu(bn0(x)) @ Uj0
//   bx 4,5: XNI = relu(bn0(x)) @ Ui0
// LDS linear [row][32] + XOR unit^(row&3): conflict-free write+read.
// ---------------------------------------------------------------------------
__global__ __launch_bounds__(256)
void gemm0_fused_kernel(const float* __restrict__ x,
                        const ushort* __restrict__ WresT, const ushort* __restrict__ W0t,
                        const float* __restrict__ sc0, const float* __restrict__ sh0,
                        ushort* __restrict__ XW, ushort* __restrict__ XNJ,
                        ushort* __restrict__ XNI)
{
    __shared__ ushort As[128 * 32];
    __shared__ ushort Bs[128 * 32];
    __shared__ float s_sc[512], s_sh[512];

    const int tid = threadIdx.x;
    const int id   = blockIdx.x;
    const int xcd  = id & 7;
    const int rest = id >> 3;
    const int slot = rest / 6;
    const int bx   = rest - slot * 6;
    const int by   = slot * 8 + xcd;

    const bool bnmode = bx >= 2;
    const ushort* Bt = bnmode ? W0t : WresT;
    const int btrow = bnmode ? (bx - 2) * 128 : bx * 128;
    ushort* Cout = (bx < 2) ? XW : (bx < 4 ? XNJ : XNI);
    const int colbase = (bx & 1) * 128;
    const int tM = by * 128;

    for (int i = tid; i < 512; i += 256) { s_sc[i] = sc0[i]; s_sh[i] = sh0[i]; }
    __syncthreads();

    const int lane = tid & 63;
    const int wave = tid >> 6;
    const int wm = wave >> 1, wn = wave & 1;
    const int lr = lane & 15, lg = lane >> 4;

    const int ra = tid >> 1;
    const int ua = (tid & 1) * 2;
    const int rb = tid >> 2;
    const int ub = tid & 3;

    f32x4 acc[4][4] = {};

    for (int k0 = 0; k0 < 512; k0 += 32) {
        const float* xp = &x[(size_t)(tM + ra) * 512 + k0 + ua * 8];
        float4 f0 = *(const float4*)(xp);
        float4 f1 = *(const float4*)(xp + 4);
        float4 f2 = *(const float4*)(xp + 8);
        float4 f3 = *(const float4*)(xp + 12);
        float vv[16] = { f0.x,f0.y,f0.z,f0.w, f1.x,f1.y,f1.z,f1.w,
                         f2.x,f2.y,f2.z,f2.w, f3.x,f3.y,f3.z,f3.w };
        ushort hh[16];
        if (bnmode) {
#pragma unroll
            for (int j = 0; j < 16; j++) {
                int c = k0 + ua * 8 + j;
                hh[j] = f2bf(fmaxf(vv[j] * s_sc[c] + s_sh[c], 0.0f));
            }
        } else {
#pragma unroll
            for (int j = 0; j < 16; j++) hh[j] = f2bf(vv[j]);
        }
        *(uint4*)&As[ra * 32 + ((ua    ) ^ (ra & 3)) * 8] = *(uint4*)&hh[0];
        *(uint4*)&As[ra * 32 + ((ua + 1) ^ (ra & 3)) * 8] = *(uint4*)&hh[8];

#pragma unroll
        for (int i = 0; i < 2; i++) {
            int row = rb + i * 64;
            *(uint4*)&Bs[row * 32 + (ub ^ (row & 3)) * 8] =
                *(const uint4*)&Bt[(size_t)(btrow + row) * 512 + k0 + ub * 8];
        }
        __syncthreads();

        bfrag af[4], bfv[4];
#pragma unroll
        for (int mm = 0; mm < 4; mm++) {
            int row = wm * 64 + mm * 16 + lr;
            af[mm] = *(const bfrag*)&As[row * 32 + (lg ^ (row & 3)) * 8];
        }
#pragma unroll
        for (int nn = 0; nn < 4; nn++) {
            int row = wn * 64 + nn * 16 + lr;
            bfv[nn] = *(const bfrag*)&Bs[row * 32 + (lg ^ (row & 3)) * 8];
        }
#pragma unroll
        for (int mm = 0; mm < 4; mm++)
#pragma unroll
            for (int nn = 0; nn < 4; nn++)
                acc[mm][nn] = __builtin_amdgcn_mfma_f32_16x16x32_bf16(af[mm], bfv[nn], acc[mm][nn], 0, 0, 0);
        __syncthreads();
    }

#pragma unroll
    for (int mm = 0; mm < 4; mm++)
#pragma unroll
        for (int nn = 0; nn < 4; nn++)
#pragma unroll
            for (int r = 0; r < 4; r++) {
                int row = tM + wm * 64 + mm * 16 + lg * 4 + r;
                int col = colbase + wn * 64 + nn * 16 + lr;
                Cout[(size_t)row * 256 + col] = f2bf(acc[mm][nn][r]);
            }
}

// ---------------------------------------------------------------------------
// Gather layer 0, persistent (2048 blocks x 8 iters), bn1 stats in registers,
// single LDS-reduce + atomics at the end (8x fewer atomics).
//   X1[d] = ui0_b + valof[d]*XNI[colof[d]] + sumA[d]*uj0_b + sum vals0*XNJ[srcs0]
// ---------------------------------------------------------------------------
__global__ __launch_bounds__(256)
void gather0_kernel(const int* __restrict__ offs, const int* __restrict__ cnt,
                    const int* __restrict__ srcs0, const float* __restrict__ vals0,
                    const int* __restrict__ colof, const float* __restrict__ valof,
                    const float* __restrict__ sumA,
                    const ushort* __restrict__ XNJ, const ushort* __restrict__ XNI,
                    const float* __restrict__ ui_b, const float* __restrict__ uj_b,
                    ushort* __restrict__ X1,
                    float* __restrict__ psum1s, float* __restrict__ psq1s)
{
    __shared__ float redS[4][256];
    __shared__ float redQ[4][256];

    int wave = threadIdx.x >> 6;
    int f = (threadIdx.x & 63) * 4;
    float ub0 = ui_b[f + 0], ub1 = ui_b[f + 1], ub2 = ui_b[f + 2], ub3 = ui_b[f + 3];
    float jb0 = uj_b[f + 0], jb1 = uj_b[f + 1], jb2 = uj_b[f + 2], jb3 = uj_b[f + 3];
    float ss0 = 0, ss1 = 0, ss2 = 0, ss3 = 0;
    float qq0 = 0, qq1 = 0, qq2 = 0, qq3 = 0;

    for (int it = 0; it < 8; it++) {
        int d = (blockIdx.x * 8 + it) * 4 + wave;
        int c = colof[d];
        float s = valof[d];
        float sA = sumA[d];
        ushort4 u = *(const ushort4*)&XNI[(size_t)c * 256 + f];
        const ushort* up = (const ushort*)&u;
        float a0 = ub0 + sA * jb0 + s * bf2f(up[0]);
        float a1 = ub1 + sA * jb1 + s * bf2f(up[1]);
        float a2 = ub2 + sA * jb2 + s * bf2f(up[2]);
        float a3 = ub3 + sA * jb3 + s * bf2f(up[3]);

        int st = offs[d], n = cnt[d];
        for (int e0 = 0; e0 < n; e0 += 4) {
            int   i0 = srcs0[st + e0];
            float w0 = vals0[st + e0];
            int i1 = 0, i2 = 0, i3 = 0;
            float w1 = 0, w2 = 0, w3 = 0;
            if (e0 + 1 < n) { i1 = srcs0[st + e0 + 1]; w1 = vals0[st + e0 + 1]; }
            if (e0 + 2 < n) { i2 = srcs0[st + e0 + 2]; w2 = vals0[st + e0 + 2]; }
            if (e0 + 3 < n) { i3 = srcs0[st + e0 + 3]; w3 = vals0[st + e0 + 3]; }
            ushort4 v0 = *(const ushort4*)&XNJ[(size_t)i0 * 256 + f];
            ushort4 v1 = *(const ushort4*)&XNJ[(size_t)i1 * 256 + f];
            ushort4 v2 = *(const ushort4*)&XNJ[(size_t)i2 * 256 + f];
            ushort4 v3 = *(const ushort4*)&XNJ[(size_t)i3 * 256 + f];
            const ushort* p0 = (const ushort*)&v0;
            const ushort* p1 = (const ushort*)&v1;
            const ushort* p2 = (const ushort*)&v2;
            const ushort* p3 = (const ushort*)&v3;
            a0 += w0 * bf2f(p0[0]) + w1 * bf2f(p1[0]) + w2 * bf2f(p2[0]) + w3 * bf2f(p3[0]);
            a1 += w0 * bf2f(p0[1]) + w1 * bf2f(p1[1]) + w2 * bf2f(p2[1]) + w3 * bf2f(p3[1]);
            a2 += w0 * bf2f(p0[2]) + w1 * bf2f(p1[2]) + w2 * bf2f(p2[2]) + w3 * bf2f(p3[2]);
            a3 += w0 * bf2f(p0[3]) + w1 * bf2f(p1[3]) + w2 * bf2f(p2[3]) + w3 * bf2f(p3[3]);
        }
        *(ushort4*)&X1[(size_t)d * 256 + f] =
            make_ushort4(f2bf(a0), f2bf(a1), f2bf(a2), f2bf(a3));
        ss0 += a0; ss1 += a1; ss2 += a2; ss3 += a3;
        qq0 += a0 * a0; qq1 += a1 * a1; qq2 += a2 * a2; qq3 += a3 * a3;
    }

    redS[wave][f + 0] = ss0; redS[wave][f + 1] = ss1;
    redS[wave][f + 2] = ss2; redS[wave][f + 3] = ss3;
    redQ[wave][f + 0] = qq0; redQ[wave][f + 1] = qq1;
    redQ[wave][f + 2] = qq2; redQ[wave][f + 3] = qq3;
    __syncthreads();
    int t = threadIdx.x;   // channel
    float ssum = redS[0][t] + redS[1][t] + redS[2][t] + redS[3][t];
    float sq   = redQ[0][t] + redQ[1][t] + redQ[2][t] + redQ[3][t];
    int slab = (blockIdx.x & 63) * 256 + t;
    atomicAdd(&psum1s[slab], ssum);
    atomicAdd(&psq1s[slab], sq);
}

// ---------------------------------------------------------------------------
// Gather layer 1 (pre-GEMM, bn1+relu folded), 4-wide batched row loads:
//   G[d] = sum_e valsA * relu(sc1*X1[srcsA] + sh1)     (bf16 out)
// ---------------------------------------------------------------------------
__global__ __launch_bounds__(256)
void gather1G_kernel(const int* __restrict__ offs, const int* __restrict__ cnt,
                     const int* __restrict__ srcsA, const float* __restrict__ valsA,
                     const ushort* __restrict__ X1,
                     const float* __restrict__ sc1, const float* __restrict__ sh1,
                     ushort* __restrict__ G)
{
    int d = blockIdx.x * 4 + (threadIdx.x >> 6);
    int f = (threadIdx.x & 63) * 4;
    float4 sc = *(const float4*)&sc1[f];
    float4 sh = *(const float4*)&sh1[f];
    float a0 = 0, a1 = 0, a2 = 0, a3 = 0;

    int st = offs[d], n = cnt[d];
    for (int e0 = 0; e0 < n; e0 += 4) {
        int   i0 = srcsA[st + e0];
        float w0 = valsA[st + e0];
        int i1 = 0, i2 = 0, i3 = 0;
        float w1 = 0, w2 = 0, w3 = 0;
        if (e0 + 1 < n) { i1 = srcsA[st + e0 + 1]; w1 = valsA[st + e0 + 1]; }
        if (e0 + 2 < n) { i2 = srcsA[st + e0 + 2]; w2 = valsA[st + e0 + 2]; }
        if (e0 + 3 < n) { i3 = srcsA[st + e0 + 3]; w3 = valsA[st + e0 + 3]; }
        ushort4 v0 = *(const ushort4*)&X1[(size_t)i0 * 256 + f];
        ushort4 v1 = *(const ushort4*)&X1[(size_t)i1 * 256 + f];
        ushort4 v2 = *(const ushort4*)&X1[(size_t)i2 * 256 + f];
        ushort4 v3 = *(const ushort4*)&X1[(size_t)i3 * 256 + f];
        const ushort* p0 = (const ushort*)&v0;
        const ushort* p1 = (const ushort*)&v1;
        const ushort* p2 = (const ushort*)&v2;
        const ushort* p3 = (const ushort*)&v3;
        a0 += w0 * fmaxf(bf2f(p0[0]) * sc.x + sh.x, 0.0f)
            + w1 * fmaxf(bf2f(p1[0]) * sc.x + sh.x, 0.0f)
            + w2 * fmaxf(bf2f(p2[0]) * sc.x + sh.x, 0.0f)
            + w3 * fmaxf(bf2f(p3[0]) * sc.x + sh.x, 0.0f);
        a1 += w0 * fmaxf(bf2f(p0[1]) * sc.y + sh.y, 0.0f)
            + w1 * fmaxf(bf2f(p1[1]) * sc.y + sh.y, 0.0f)
            + w2 * fmaxf(bf2f(p2[1]) * sc.y + sh.y, 0.0f)
            + w3 * fmaxf(bf2f(p3[1]) * sc.y + sh.y, 0.0f);
        a2 += w0 * fmaxf(bf2f(p0[2]) * sc.z + sh.z, 0.0f)
            + w1 * fmaxf(bf2f(p1[2]) * sc.z + sh.z, 0.0f)
            + w2 * fmaxf(bf2f(p2[2]) * sc.z + sh.z, 0.0f)
            + w3 * fmaxf(bf2f(p3[2]) * sc.z + sh.z, 0.0f);
        a3 += w0 * fmaxf(bf2f(p0[3]) * sc.w + sh.w, 0.0f)
            + w1 * fmaxf(bf2f(p1[3]) * sc.w + sh.w, 0.0f)
            + w2 * fmaxf(bf2f(p2[3]) * sc.w + sh.w, 0.0f)
            + w3 * fmaxf(bf2f(p3[3]) * sc.w + sh.w, 0.0f);
    }
    *(ushort4*)&G[(size_t)d * 256 + f] =
        make_ushort4(f2bf(a0), f2bf(a1), f2bf(a2), f2bf(a3));
}

// ---------------------------------------------------------------------------
// GEMM final: out[65536,256] f32 = [relu(bn1(X1)) | G] @ W1cat^T + biases + res
// 256x256 tile, 512 thr (8 waves 4x2, wave tile 64x128), grid 256 (1 blk/CU).
// ---------------------------------------------------------------------------
__global__ __launch_bounds__(512, 1)
void gemm_final_kernel(const ushort* __restrict__ X1, const ushort* __restrict__ G,
                       const ushort* __restrict__ W1cat,
                       const float* __restrict__ sc1, const float* __restrict__ sh1,
                       const float* __restrict__ biasUi, const float* __restrict__ uj1_b,
                       const float* __restrict__ sumA,
                       const int* __restrict__ colof, const float* __restrict__ valof,
                       const ushort* __restrict__ XW,
                       float* __restrict__ out)
{
    __shared__ ushort As[256 * 32];
    __shared__ ushort Bs[256 * 32];
    __shared__ float s_sc[256], s_sh[256];

    const int tid = threadIdx.x;
    const int tM = blockIdx.x * 256;

    if (tid < 256) { s_sc[tid] = sc1[tid]; s_sh[tid] = sh1[tid]; }
    __syncthreads();

    const int lane = tid & 63;
    const int wave = tid >> 6;
    const int wm = wave >> 1, wn = wave & 1;    // wave tile 64 rows x 128 cols
    const int lr = lane & 15, lg = lane >> 4;

    f32x4 acc[4][8] = {};

    for (int k0 = 0; k0 < 512; k0 += 32) {
        // --- A stage: 256 rows x 4 units, 2 per thread ---
#pragma unroll
        for (int i = 0; i < 2; i++) {
            int idx = tid + i * 512;
            int row = idx >> 2, u = idx & 3;
            ushort h[8];
            if (k0 < 256) {
                *(uint4*)h = *(const uint4*)&X1[(size_t)(tM + row) * 256 + k0 + u * 8];
#pragma unroll
                for (int j = 0; j < 8; j++) {
                    int c = k0 + u * 8 + j;
                    h[j] = f2bf(fmaxf(bf2f(h[j]) * s_sc[c] + s_sh[c], 0.0f));
                }
            } else {
                *(uint4*)h = *(const uint4*)&G[(size_t)(tM + row) * 256 + (k0 - 256) + u * 8];
            }
            *(uint4*)&As[row * 32 + (u ^ (row & 3)) * 8] = *(uint4*)h;
        }
        // --- B stage: 256 rows x 4 units, 2 per thread ---
#pragma unroll
        for (int i = 0; i < 2; i++) {
            int idx = tid + i * 512;
            int row = idx >> 2, u = idx & 3;
            *(uint4*)&Bs[row * 32 + (u ^ (row & 3)) * 8] =
                *(const uint4*)&W1cat[(size_t)row * 512 + k0 + u * 8];
        }
        __syncthreads();

        bfrag af[4], bfv[8];
#pragma unroll
        for (int mm = 0; mm < 4; mm++) {
            int row = wm * 64 + mm * 16 + lr;
            af[mm] = *(const bfrag*)&As[row * 32 + (lg ^ (row & 3)) * 8];
        }
#pragma unroll
        for (int nn = 0; nn < 8; nn++) {
            int row = wn * 128 + nn * 16 + lr;
            bfv[nn] = *(const bfrag*)&Bs[row * 32 + (lg ^ (row & 3)) * 8];
        }
#pragma unroll
        for (int mm = 0; mm < 4; mm++)
#pragma unroll
            for (int nn = 0; nn < 8; nn++)
                acc[mm][nn] = __builtin_amdgcn_mfma_f32_16x16x32_bf16(af[mm], bfv[nn], acc[mm][nn], 0, 0, 0);
        __syncthreads();
    }

    // epilogue
    float bUi[8], bUj[8];
#pragma unroll
    for (int nn = 0; nn < 8; nn++) {
        int col = wn * 128 + nn * 16 + lr;
        bUi[nn] = biasUi[col];
        bUj[nn] = uj1_b[col];
    }
#pragma unroll
    for (int mm = 0; mm < 4; mm++) {
#pragma unroll
        for (int r = 0; r < 4; r++) {
            int row = tM + wm * 64 + mm * 16 + lg * 4 + r;
            int c = colof[row];
            float s = valof[row];
            float sA = sumA[row];
#pragma unroll
            for (int nn = 0; nn < 8; nn++) {
                int col = wn * 128 + nn * 16 + lr;
                float v = acc[mm][nn][r] + bUi[nn] + sA * bUj[nn]
                        + s * bf2f(XW[(size_t)c * 256 + col]);
                out[(size_t)row * 256 + col] = v;
            }
        }
    }
}

// ---------------------------------------------------------------------------
// Host launcher
// ---------------------------------------------------------------------------
extern "C" void kernel_launch(void* const* d_in, const int* in_sizes, int n_in,
                              void* d_out, int out_size, void* d_ws, size_t ws_size,
                              hipStream_t stream)
{
    const float* x      = (const float*)d_in[0];
    const int*   up_row = (const int*)  d_in[1];
    const int*   up_col = (const int*)  d_in[2];
    const float* up_val = (const float*)d_in[3];
    const int*   e_src  = (const int*)  d_in[4];
    const int*   e_dst  = (const int*)  d_in[5];
    const float* adjv   = (const float*)d_in[6];
    const float* W_res  = (const float*)d_in[7];
    const float* b_res  = (const float*)d_in[8];
    const float* bn0_g  = (const float*)d_in[9];
    const float* bn0_b  = (const float*)d_in[10];
    const float* bn1_g  = (const float*)d_in[11];
    const float* bn1_b  = (const float*)d_in[12];
    const float* Ui0_W  = (const float*)d_in[13];
    const float* Ui0_b  = (const float*)d_in[14];
    const float* Uj0_W  = (const float*)d_in[15];
    const float* Uj0_b  = (const float*)d_in[16];
    const float* Ui1_W  = (const float*)d_in[17];
    const float* Ui1_b  = (const float*)d_in[18];
    const float* Uj1_W  = (const float*)d_in[19];
    const float* Uj1_b  = (const float*)d_in[20];

    float* out = (float*)d_out;

    // ---- workspace layout ----
    char* ws = (char*)d_ws;
    size_t off = 0;
    auto alloc = [&](size_t bytes) -> char* {
        char* p = ws + off;
        off = (off + bytes + 255) & ~(size_t)255;
        return p;
    };
    ushort* XW    = (ushort*)alloc((size_t)V_PREV * F_OUT * 2);   // 8.4 MB
    ushort* XNJ   = (ushort*)alloc((size_t)V_PREV * F_OUT * 2);   // 8.4 MB
    ushort* XNI   = (ushort*)alloc((size_t)V_PREV * F_OUT * 2);   // 8.4 MB
    ushort* X1    = (ushort*)alloc((size_t)V_NEXT * F_OUT * 2);   // 33.6 MB
    ushort* G     = (ushort*)alloc((size_t)V_NEXT * F_OUT * 2);   // 33.6 MB
    // --- zeroed region (prep_all): cnt, sumA, psum1s, psq1s (163840 ints) ---
    int*    cnt   = (int*)   alloc(V_NEXT * 4);                   // 256 KB
    float*  sumA  = (float*) alloc(V_NEXT * 4);                   // 256 KB
    float*  psum1s= (float*) alloc(64 * 256 * 4);                 // 64 KB
    float*  psq1s = (float*) alloc(64 * 256 * 4);                 // 64 KB
    int*    offs  = (int*)   alloc(V_NEXT * 4);
    int*    cursor= (int*)   alloc(V_NEXT * 4);
    int*    bsum  = (int*)   alloc(256 * 4);
    int*    srcsA = (int*)   alloc((size_t)N_EDGE * 4);
    float*  valsA = (float*) alloc((size_t)N_EDGE * 4);
    int*    srcs0 = (int*)   alloc((size_t)N_EDGE * 4);
    float*  vals0 = (float*) alloc((size_t)N_EDGE * 4);
    int*    colof = (int*)   alloc(V_NEXT * 4);
    float*  valof = (float*) alloc(V_NEXT * 4);
    ushort* WresT = (ushort*)alloc(256 * 512 * 2);
    ushort* W0t   = (ushort*)alloc(512 * 512 * 2);
    ushort* W1cat = (ushort*)alloc(256 * 512 * 2);
    float*  biasUi= (float*) alloc(256 * 4);
    float*  psum0 = (float*) alloc(128 * 512 * 4);
    float*  psq0  = (float*) alloc(128 * 512 * 4);
    float*  sc0   = (float*) alloc(512 * 4);
    float*  sh0   = (float*) alloc(512 * 4);
    float*  sc1   = (float*) alloc(256 * 4);
    float*  sh1   = (float*) alloc(256 * 4);
    (void)ws_size; (void)in_sizes; (void)n_in; (void)out_size;

    // ---- K1: weight prep + up invert + zero counters ----
    prep_all_kernel<<<1920, 256, 0, stream>>>(W_res, Ui0_W, Uj0_W, Ui1_W, Uj1_W,
                                              Ui1_b, b_res,
                                              up_row, up_col, up_val,
                                              WresT, W0t, W1cat, biasUi,
                                              colof, valof, cnt);

    // ---- K2: histogram + bn0 partial stats ----
    hist_bn0_kernel<<<2176, 256, 0, stream>>>(e_dst, adjv, cnt, sumA, x, psum0, psq0);

    // ---- K3: block scan ----
    scan_block_kernel<<<256, 256, 0, stream>>>(cnt, offs, bsum);

    // ---- K4: offset add + bn0 finish ----
    add_offs_bnfin_kernel<<<384, 256, 0, stream>>>(offs, bsum, cursor,
                                                   psum0, psq0, bn0_g, bn0_b, sc0, sh0);

    // ---- K5: edge fill (dst-sorted, up-map pre-composed) ----
    fill_kernel<<<N_EDGE / 256, 256, 0, stream>>>(e_src, e_dst, adjv, colof, valof,
                                                  cursor, srcsA, valsA, srcs0, vals0);

    // ---- K6: GEMM0 (fused bn0+relu+cast, XCD-grouped): XW, XNJ, XNI ----
    gemm0_fused_kernel<<<768, 256, 0, stream>>>(x, WresT, W0t, sc0, sh0, XW, XNJ, XNI);

    // ---- K7: ECC layer 0 aggregation + bn1 stats (persistent) ----
    gather0_kernel<<<2048, 256, 0, stream>>>(offs, cnt, srcs0, vals0,
                                             colof, valof, sumA,
                                             XNJ, XNI, Ui0_b, Uj0_b, X1,
                                             psum1s, psq1s);

    // ---- K8: bn1 finish ----
    bn_finish_kernel<<<64, 256, 0, stream>>>(psum1s, psq1s, 64, 256, 1.0f / V_NEXT,
                                             bn1_g, bn1_b, sc1, sh1);

    // ---- K9: ECC layer 1 aggregation (commuted) ----
    gather1G_kernel<<<V_NEXT / 4, 256, 0, stream>>>(offs, cnt, srcsA, valsA,
                                                    X1, sc1, sh1, G);

    // ---- K10: final GEMM: out = [H1|G] @ W1cat + biases + residual ----
    gemm_final_kernel<<<256, 512, 0, stream>>>(X1, G, W1cat, sc1, sh1,
                                               biasUi, Uj1_b, sumA,
                                               colof, valof, XW, out);
}

// Round 11
// 238.146 us; speedup vs baseline: 1.4006x; 1.1519x over previous
//
#include <hip/hip_runtime.h>

// ---------------------------------------------------------------------------
// Problem constants
// ---------------------------------------------------------------------------
#define V_PREV 16384
#define V_NEXT 65536
#define F_IN   512
#define F_OUT  256
#define NNZ_UP 65536
#define N_EDGE 524288

using f32x4 = __attribute__((ext_vector_type(4))) float;
using bfrag = __attribute__((ext_vector_type(8))) short;   // 8 x bf16

__device__ __forceinline__ ushort f2bf(float f) {
    union { float f; unsigned u; } v; v.f = f;
    unsigned r = (v.u + 0x7FFFu + ((v.u >> 16) & 1u)) >> 16;
    return (ushort)r;
}
__device__ __forceinline__ float bf2f(ushort h) {
    union { unsigned u; float f; } v; v.u = ((unsigned)h) << 16; return v.f;
}

// ---------------------------------------------------------------------------
// Fat kernel 1: prep_weights (0..1023) + invert_up (1024..1279)
//             + zero cnt/psum1s/psq1s (1280..1663)
// ---------------------------------------------------------------------------
__global__ void prep_all_kernel(const float* __restrict__ Wres,
                                const float* __restrict__ Ui0W, const float* __restrict__ Uj0W,
                                const float* __restrict__ Ui1W, const float* __restrict__ Uj1W,
                                const float* __restrict__ Ui1b, const float* __restrict__ bres,
                                const int* __restrict__ up_row, const int* __restrict__ up_col,
                                const float* __restrict__ up_val,
                                ushort* __restrict__ WresT, ushort* __restrict__ W0t,
                                ushort* __restrict__ W1cat, float* __restrict__ biasUi,
                                int* __restrict__ colof, float* __restrict__ valof,
                                int* __restrict__ zeroBase)
{
    int b = blockIdx.x, t = threadIdx.x;
    if (b < 1024) {
        int i = b * 256 + t;                      // 0 .. 262143
        if (i < 256 * 512) {
            int n = i / 512, k = i % 512;
            WresT[i] = f2bf(Wres[k * 256 + n]);
            W1cat[i] = f2bf(k < 256 ? Ui1W[k * 256 + n] : Uj1W[(k - 256) * 256 + n]);
        }
        {
            int n = i / 512, k = i % 512;
            W0t[i] = f2bf(n < 256 ? Uj0W[k * 256 + n] : Ui0W[k * 256 + (n - 256)]);
        }
        if (i < 256) biasUi[i] = Ui1b[i] + bres[i];
    } else if (b < 1280) {
        int k = (b - 1024) * 256 + t;             // 0 .. 65535
        int r = up_row[k];
        colof[r] = up_col[k];
        valof[r] = up_val[k];
    } else {
        int i = (b - 1280) * 256 + t;             // 0 .. 98303
        zeroBase[i] = 0;
    }
}

// ---------------------------------------------------------------------------
// Fat kernel 2: hist cnt-only (0..2047) + bn0_part 512 blocks (2048..2559)
// ---------------------------------------------------------------------------
__global__ void hist_bn0_kernel(const int* __restrict__ dst,
                                int* __restrict__ cnt,
                                const float* __restrict__ x,
                                float* __restrict__ psum0, float* __restrict__ psq0)
{
    int b = blockIdx.x, t = threadIdx.x;
    if (b < 2048) {
        int e = b * 256 + t;
        atomicAdd(&cnt[dst[e]], 1);
    } else {
        int blk = b - 2048;                        // 0..511, 32 rows each
        float s0 = 0, s1 = 0, q0 = 0, q1 = 0;
        for (int r = 0; r < 32; r++) {
            size_t base = ((size_t)blk * 32 + r) * 512;
            float a = x[base + t], bb = x[base + t + 256];
            s0 += a; q0 += a * a; s1 += bb; q1 += bb * bb;
        }
        psum0[blk * 512 + t] = s0; psum0[blk * 512 + t + 256] = s1;
        psq0 [blk * 512 + t] = q0; psq0 [blk * 512 + t + 256] = q1;
    }
}

// ---------------------------------------------------------------------------
// CSR scan
// ---------------------------------------------------------------------------
__global__ void scan_block_kernel(const int* __restrict__ cnt, int* __restrict__ offs,
                                  int* __restrict__ bsum)
{
    __shared__ int buf[2][256];
    int t = threadIdx.x;
    int i = blockIdx.x * 256 + t;
    int v = cnt[i];
    int p = 0;
    buf[0][t] = v;
    __syncthreads();
    for (int d = 1; d < 256; d <<= 1) {
        int nv = buf[p][t] + ((t >= d) ? buf[p][t - d] : 0);
        buf[p ^ 1][t] = nv;
        p ^= 1;
        __syncthreads();
    }
    int incl = buf[p][t];
    offs[i] = incl - v;
    if (t == 255) bsum[blockIdx.x] = incl;
}

// Fat kernel 3: add_offs2 (0..255) + bn0 finish (256..383, nblocks=512)
__global__ void add_offs_bnfin_kernel(int* __restrict__ offs, const int* __restrict__ bsum,
                                      int* __restrict__ cursor,
                                      const float* __restrict__ psum0, const float* __restrict__ psq0,
                                      const float* __restrict__ g0, const float* __restrict__ b0,
                                      float* __restrict__ sc0, float* __restrict__ sh0)
{
    int b = blockIdx.x, t = threadIdx.x;
    if (b < 256) {
        __shared__ int buf[2][256];
        int v = bsum[t];
        int p = 0;
        buf[0][t] = v;
        __syncthreads();
        for (int d = 1; d < 256; d <<= 1) {
            int nv = buf[p][t] + ((t >= d) ? buf[p][t - d] : 0);
            buf[p ^ 1][t] = nv;
            p ^= 1;
            __syncthreads();
        }
        int excl = buf[p][b] - bsum[b];
        int i = b * 256 + t;
        int o = offs[i] + excl;
        offs[i] = o;
        cursor[i] = o;
    } else {
        int vb = b - 256;                          // 0..127
        int gw = (vb * 256 + t) >> 6;              // channel 0..511
        int lane = t & 63;
        float s = 0, q = 0;
        for (int i = lane; i < 512; i += 64) {
            s += psum0[(size_t)i * 512 + gw];
            q += psq0 [(size_t)i * 512 + gw];
        }
#pragma unroll
        for (int d = 32; d > 0; d >>= 1) {
            s += __shfl_xor(s, d);
            q += __shfl_xor(q, d);
        }
        if (lane == 0) {
            float m = s * (1.0f / V_PREV);
            float v = q * (1.0f / V_PREV) - m * m;
            float r = rsqrtf(v + 1e-5f);
            float scale = r * g0[gw];
            sc0[gw] = scale;
            sh0[gw] = b0[gw] - m * scale;
        }
    }
}

// bn1 finish (standalone)
__global__ void bn_finish_kernel(const float* __restrict__ psum, const float* __restrict__ psq,
                                 int nblocks, int C, float invN,
                                 const float* __restrict__ g, const float* __restrict__ b,
                                 float* __restrict__ sc, float* __restrict__ sh)
{
    int gw = (blockIdx.x * blockDim.x + threadIdx.x) >> 6;
    int lane = threadIdx.x & 63;
    if (gw >= C) return;
    float s = 0, q = 0;
    for (int i = lane; i < nblocks; i += 64) {
        s += psum[(size_t)i * C + gw];
        q += psq [(size_t)i * C + gw];
    }
#pragma unroll
    for (int d = 32; d > 0; d >>= 1) {
        s += __shfl_xor(s, d);
        q += __shfl_xor(q, d);
    }
    if (lane == 0) {
        float m = s * invN;
        float v = q * invN - m * m;
        float r = rsqrtf(v + 1e-5f);
        float scale = r * g[gw];
        sc[gw] = scale;
        sh[gw] = b[gw] - m * scale;
    }
}

// ---------------------------------------------------------------------------
// Fat kernel 4: fill (0..2047) + gemm0 (2048..2815, XCD-grouped)
// fill: E[p] = {srcA, valA, src0=colof[srcA], val0=valA*valof[srcA]}, 16B store
// gemm0: bx 0,1: XW = bf16(x)@WresT; 2,3: XNJ = bn-relu(x)@Uj0; 4,5: XNI @Ui0
// ---------------------------------------------------------------------------
__global__ __launch_bounds__(256)
void fill_gemm0_kernel(const int* __restrict__ src, const int* __restrict__ dst,
                       const float* __restrict__ adjv,
                       const int* __restrict__ colof, const float* __restrict__ valof,
                       int* __restrict__ cursor, int4* __restrict__ E,
                       const float* __restrict__ x,
                       const ushort* __restrict__ WresT, const ushort* __restrict__ W0t,
                       const float* __restrict__ sc0, const float* __restrict__ sh0,
                       ushort* __restrict__ XW, ushort* __restrict__ XNJ,
                       ushort* __restrict__ XNI)
{
    __shared__ ushort As[128 * 32];
    __shared__ ushort Bs[128 * 32];
    __shared__ float s_sc[512], s_sh[512];

    const int tid = threadIdx.x;
    if (blockIdx.x < 2048) {
        int e = blockIdx.x * 256 + tid;
        int d = dst[e];
        int s = src[e];
        float a = adjv[e];
        int p = atomicAdd(&cursor[d], 1);
        int4 v;
        v.x = s;
        v.y = __float_as_int(a);
        v.z = colof[s];
        v.w = __float_as_int(a * valof[s]);
        E[p] = v;
        return;
    }

    const int id   = blockIdx.x - 2048;        // 0..767 (2048%8==0 keeps XCD phase)
    const int xcd  = id & 7;
    const int rest = id >> 3;
    const int slot = rest / 6;
    const int bx   = rest - slot * 6;
    const int by   = slot * 8 + xcd;

    const bool bnmode = bx >= 2;
    const ushort* Bt = bnmode ? W0t : WresT;
    const int btrow = bnmode ? (bx - 2) * 128 : bx * 128;
    ushort* Cout = (bx < 2) ? XW : (bx < 4 ? XNJ : XNI);
    const int colbase = (bx & 1) * 128;
    const int tM = by * 128;

    for (int i = tid; i < 512; i += 256) { s_sc[i] = sc0[i]; s_sh[i] = sh0[i]; }
    __syncthreads();

    const int lane = tid & 63;
    const int wave = tid >> 6;
    const int wm = wave >> 1, wn = wave & 1;
    const int lr = lane & 15, lg = lane >> 4;

    const int ra = tid >> 1;
    const int ua = (tid & 1) * 2;
    const int rb = tid >> 2;
    const int ub = tid & 3;

    f32x4 acc[4][4] = {};

    for (int k0 = 0; k0 < 512; k0 += 32) {
        const float* xp = &x[(size_t)(tM + ra) * 512 + k0 + ua * 8];
        float4 f0 = *(const float4*)(xp);
        float4 f1 = *(const float4*)(xp + 4);
        float4 f2 = *(const float4*)(xp + 8);
        float4 f3 = *(const float4*)(xp + 12);
        float vv[16] = { f0.x,f0.y,f0.z,f0.w, f1.x,f1.y,f1.z,f1.w,
                         f2.x,f2.y,f2.z,f2.w, f3.x,f3.y,f3.z,f3.w };
        ushort hh[16];
        if (bnmode) {
#pragma unroll
            for (int j = 0; j < 16; j++) {
                int c = k0 + ua * 8 + j;
                hh[j] = f2bf(fmaxf(vv[j] * s_sc[c] + s_sh[c], 0.0f));
            }
        } else {
#pragma unroll
            for (int j = 0; j < 16; j++) hh[j] = f2bf(vv[j]);
        }
        *(uint4*)&As[ra * 32 + ((ua    ) ^ (ra & 3)) * 8] = *(uint4*)&hh[0];
        *(uint4*)&As[ra * 32 + ((ua + 1) ^ (ra & 3)) * 8] = *(uint4*)&hh[8];

#pragma unroll
        for (int i = 0; i < 2; i++) {
            int row = rb + i * 64;
            *(uint4*)&Bs[row * 32 + (ub ^ (row & 3)) * 8] =
                *(const uint4*)&Bt[(size_t)(btrow + row) * 512 + k0 + ub * 8];
        }
        __syncthreads();

        bfrag af[4], bfv[4];
#pragma unroll
        for (int mm = 0; mm < 4; mm++) {
            int row = wm * 64 + mm * 16 + lr;
            af[mm] = *(const bfrag*)&As[row * 32 + (lg ^ (row & 3)) * 8];
        }
#pragma unroll
        for (int nn = 0; nn < 4; nn++) {
            int row = wn * 64 + nn * 16 + lr;
            bfv[nn] = *(const bfrag*)&Bs[row * 32 + (lg ^ (row & 3)) * 8];
        }
#pragma unroll
        for (int mm = 0; mm < 4; mm++)
#pragma unroll
            for (int nn = 0; nn < 4; nn++)
                acc[mm][nn] = __builtin_amdgcn_mfma_f32_16x16x32_bf16(af[mm], bfv[nn], acc[mm][nn], 0, 0, 0);
        __syncthreads();
    }

#pragma unroll
    for (int mm = 0; mm < 4; mm++)
#pragma unroll
        for (int nn = 0; nn < 4; nn++)
#pragma unroll
            for (int r = 0; r < 4; r++) {
                int row = tM + wm * 64 + mm * 16 + lg * 4 + r;
                int col = colbase + wn * 64 + nn * 16 + lr;
                Cout[(size_t)row * 256 + col] = f2bf(acc[mm][nn][r]);
            }
}

// ---------------------------------------------------------------------------
// Gather layer 0, persistent (2048 blocks x 8 iters), bn1 stats in registers.
//   X1[d] = ui0_b + valof[d]*XNI[colof[d]] + sumA*uj0_b + sum val0*XNJ[src0]
//   sumA[d] computed on the fly (edge valA) and written for gemm_final.
// ---------------------------------------------------------------------------
__global__ __launch_bounds__(256)
void gather0_kernel(const int* __restrict__ offs, const int* __restrict__ cnt,
                    const int4* __restrict__ E,
                    const int* __restrict__ colof, const float* __restrict__ valof,
                    const ushort* __restrict__ XNJ, const ushort* __restrict__ XNI,
                    const float* __restrict__ ui_b, const float* __restrict__ uj_b,
                    ushort* __restrict__ X1, float* __restrict__ sumA,
                    float* __restrict__ psum1s, float* __restrict__ psq1s)
{
    __shared__ float redS[4][256];
    __shared__ float redQ[4][256];

    int wave = threadIdx.x >> 6;
    int lane = threadIdx.x & 63;
    int f = lane * 4;
    float ub0 = ui_b[f + 0], ub1 = ui_b[f + 1], ub2 = ui_b[f + 2], ub3 = ui_b[f + 3];
    float jb0 = uj_b[f + 0], jb1 = uj_b[f + 1], jb2 = uj_b[f + 2], jb3 = uj_b[f + 3];
    float ss0 = 0, ss1 = 0, ss2 = 0, ss3 = 0;
    float qq0 = 0, qq1 = 0, qq2 = 0, qq3 = 0;

    for (int it = 0; it < 8; it++) {
        int d = (blockIdx.x * 8 + it) * 4 + wave;
        int c = colof[d];
        float s = valof[d];
        ushort4 u = *(const ushort4*)&XNI[(size_t)c * 256 + f];
        const ushort* up = (const ushort*)&u;
        float a0 = ub0 + s * bf2f(up[0]);
        float a1 = ub1 + s * bf2f(up[1]);
        float a2 = ub2 + s * bf2f(up[2]);
        float a3 = ub3 + s * bf2f(up[3]);
        float sA = 0;

        int st = offs[d], n = cnt[d];
        for (int e0 = 0; e0 < n; e0 += 4) {
            int4 ev0 = E[st + e0];
            int4 ev1 = (e0 + 1 < n) ? E[st + e0 + 1] : make_int4(0, 0, 0, 0);
            int4 ev2 = (e0 + 2 < n) ? E[st + e0 + 2] : make_int4(0, 0, 0, 0);
            int4 ev3 = (e0 + 3 < n) ? E[st + e0 + 3] : make_int4(0, 0, 0, 0);
            float w0 = __int_as_float(ev0.w), w1 = __int_as_float(ev1.w);
            float w2 = __int_as_float(ev2.w), w3 = __int_as_float(ev3.w);
            sA += __int_as_float(ev0.y) + __int_as_float(ev1.y)
                + __int_as_float(ev2.y) + __int_as_float(ev3.y);
            ushort4 v0 = *(const ushort4*)&XNJ[(size_t)ev0.z * 256 + f];
            ushort4 v1 = *(const ushort4*)&XNJ[(size_t)ev1.z * 256 + f];
            ushort4 v2 = *(const ushort4*)&XNJ[(size_t)ev2.z * 256 + f];
            ushort4 v3 = *(const ushort4*)&XNJ[(size_t)ev3.z * 256 + f];
            const ushort* p0 = (const ushort*)&v0;
            const ushort* p1 = (const ushort*)&v1;
            const ushort* p2 = (const ushort*)&v2;
            const ushort* p3 = (const ushort*)&v3;
            a0 += w0 * bf2f(p0[0]) + w1 * bf2f(p1[0]) + w2 * bf2f(p2[0]) + w3 * bf2f(p3[0]);
            a1 += w0 * bf2f(p0[1]) + w1 * bf2f(p1[1]) + w2 * bf2f(p2[1]) + w3 * bf2f(p3[1]);
            a2 += w0 * bf2f(p0[2]) + w1 * bf2f(p1[2]) + w2 * bf2f(p2[2]) + w3 * bf2f(p3[2]);
            a3 += w0 * bf2f(p0[3]) + w1 * bf2f(p1[3]) + w2 * bf2f(p2[3]) + w3 * bf2f(p3[3]);
        }
        a0 += sA * jb0; a1 += sA * jb1; a2 += sA * jb2; a3 += sA * jb3;
        *(ushort4*)&X1[(size_t)d * 256 + f] =
            make_ushort4(f2bf(a0), f2bf(a1), f2bf(a2), f2bf(a3));
        if (lane == 0) sumA[d] = sA;
        ss0 += a0; ss1 += a1; ss2 += a2; ss3 += a3;
        qq0 += a0 * a0; qq1 += a1 * a1; qq2 += a2 * a2; qq3 += a3 * a3;
    }

    redS[wave][f + 0] = ss0; redS[wave][f + 1] = ss1;
    redS[wave][f + 2] = ss2; redS[wave][f + 3] = ss3;
    redQ[wave][f + 0] = qq0; redQ[wave][f + 1] = qq1;
    redQ[wave][f + 2] = qq2; redQ[wave][f + 3] = qq3;
    __syncthreads();
    int t = threadIdx.x;   // channel
    float ssum = redS[0][t] + redS[1][t] + redS[2][t] + redS[3][t];
    float sq   = redQ[0][t] + redQ[1][t] + redQ[2][t] + redQ[3][t];
    int slab = (blockIdx.x & 63) * 256 + t;
    atomicAdd(&psum1s[slab], ssum);
    atomicAdd(&psq1s[slab], sq);
}

// ---------------------------------------------------------------------------
// Gather layer 1 (pre-GEMM, bn1+relu folded):
//   G[d] = sum_e valA * relu(sc1*X1[srcA] + sh1)     (bf16 out)
// ---------------------------------------------------------------------------
__global__ __launch_bounds__(256)
void gather1G_kernel(const int* __restrict__ offs, const int* __restrict__ cnt,
                     const int4* __restrict__ E,
                     const ushort* __restrict__ X1,
                     const float* __restrict__ sc1, const float* __restrict__ sh1,
                     ushort* __restrict__ G)
{
    int d = blockIdx.x * 4 + (threadIdx.x >> 6);
    int f = (threadIdx.x & 63) * 4;
    float4 sc = *(const float4*)&sc1[f];
    float4 sh = *(const float4*)&sh1[f];
    float a0 = 0, a1 = 0, a2 = 0, a3 = 0;

    int st = offs[d], n = cnt[d];
    for (int e0 = 0; e0 < n; e0 += 4) {
        int4 ev0 = E[st + e0];
        int4 ev1 = (e0 + 1 < n) ? E[st + e0 + 1] : make_int4(0, 0, 0, 0);
        int4 ev2 = (e0 + 2 < n) ? E[st + e0 + 2] : make_int4(0, 0, 0, 0);
        int4 ev3 = (e0 + 3 < n) ? E[st + e0 + 3] : make_int4(0, 0, 0, 0);
        float w0 = __int_as_float(ev0.y), w1 = __int_as_float(ev1.y);
        float w2 = __int_as_float(ev2.y), w3 = __int_as_float(ev3.y);
        ushort4 v0 = *(const ushort4*)&X1[(size_t)ev0.x * 256 + f];
        ushort4 v1 = *(const ushort4*)&X1[(size_t)ev1.x * 256 + f];
        ushort4 v2 = *(const ushort4*)&X1[(size_t)ev2.x * 256 + f];
        ushort4 v3 = *(const ushort4*)&X1[(size_t)ev3.x * 256 + f];
        const ushort* p0 = (const ushort*)&v0;
        const ushort* p1 = (const ushort*)&v1;
        const ushort* p2 = (const ushort*)&v2;
        const ushort* p3 = (const ushort*)&v3;
        a0 += w0 * fmaxf(bf2f(p0[0]) * sc.x + sh.x, 0.0f)
            + w1 * fmaxf(bf2f(p1[0]) * sc.x + sh.x, 0.0f)
            + w2 * fmaxf(bf2f(p2[0]) * sc.x + sh.x, 0.0f)
            + w3 * fmaxf(bf2f(p3[0]) * sc.x + sh.x, 0.0f);
        a1 += w0 * fmaxf(bf2f(p0[1]) * sc.y + sh.y, 0.0f)
            + w1 * fmaxf(bf2f(p1[1]) * sc.y + sh.y, 0.0f)
            + w2 * fmaxf(bf2f(p2[1]) * sc.y + sh.y, 0.0f)
            + w3 * fmaxf(bf2f(p3[1]) * sc.y + sh.y, 0.0f);
        a2 += w0 * fmaxf(bf2f(p0[2]) * sc.z + sh.z, 0.0f)
            + w1 * fmaxf(bf2f(p1[2]) * sc.z + sh.z, 0.0f)
            + w2 * fmaxf(bf2f(p2[2]) * sc.z + sh.z, 0.0f)
            + w3 * fmaxf(bf2f(p3[2]) * sc.z + sh.z, 0.0f);
        a3 += w0 * fmaxf(bf2f(p0[3]) * sc.w + sh.w, 0.0f)
            + w1 * fmaxf(bf2f(p1[3]) * sc.w + sh.w, 0.0f)
            + w2 * fmaxf(bf2f(p2[3]) * sc.w + sh.w, 0.0f)
            + w3 * fmaxf(bf2f(p3[3]) * sc.w + sh.w, 0.0f);
    }
    *(ushort4*)&G[(size_t)d * 256 + f] =
        make_ushort4(f2bf(a0), f2bf(a1), f2bf(a2), f2bf(a3));
}

// ---------------------------------------------------------------------------
// GEMM final: out[65536,256] f32 = [relu(bn1(X1)) | G] @ W1cat^T + biases + res
// 256x256 tile, 512 thr (8 waves 4x2, wave tile 64x128), grid 256 (1 blk/CU).
// ---------------------------------------------------------------------------
__global__ __launch_bounds__(512, 1)
void gemm_final_kernel(const ushort* __restrict__ X1, const ushort* __restrict__ G,
                       const ushort* __restrict__ W1cat,
                       const float* __restrict__ sc1, const float* __restrict__ sh1,
                       const float* __restrict__ biasUi, const float* __restrict__ uj1_b,
                       const float* __restrict__ sumA,
                       const int* __restrict__ colof, const float* __restrict__ valof,
                       const ushort* __restrict__ XW,
                       float* __restrict__ out)
{
    __shared__ ushort As[256 * 32];
    __shared__ ushort Bs[256 * 32];
    __shared__ float s_sc[256], s_sh[256];

    const int tid = threadIdx.x;
    const int tM = blockIdx.x * 256;

    if (tid < 256) { s_sc[tid] = sc1[tid]; s_sh[tid] = sh1[tid]; }
    __syncthreads();

    const int lane = tid & 63;
    const int wave = tid >> 6;
    const int wm = wave >> 1, wn = wave & 1;    // wave tile 64 rows x 128 cols
    const int lr = lane & 15, lg = lane >> 4;

    f32x4 acc[4][8] = {};

    for (int k0 = 0; k0 < 512; k0 += 32) {
#pragma unroll
        for (int i = 0; i < 2; i++) {
            int idx = tid + i * 512;
            int row = idx >> 2, u = idx & 3;
            ushort h[8];
            if (k0 < 256) {
                *(uint4*)h = *(const uint4*)&X1[(size_t)(tM + row) * 256 + k0 + u * 8];
#pragma unroll
                for (int j = 0; j < 8; j++) {
                    int c = k0 + u * 8 + j;
                    h[j] = f2bf(fmaxf(bf2f(h[j]) * s_sc[c] + s_sh[c], 0.0f));
                }
            } else {
                *(uint4*)h = *(const uint4*)&G[(size_t)(tM + row) * 256 + (k0 - 256) + u * 8];
            }
            *(uint4*)&As[row * 32 + (u ^ (row & 3)) * 8] = *(uint4*)h;
        }
#pragma unroll
        for (int i = 0; i < 2; i++) {
            int idx = tid + i * 512;
            int row = idx >> 2, u = idx & 3;
            *(uint4*)&Bs[row * 32 + (u ^ (row & 3)) * 8] =
                *(const uint4*)&W1cat[(size_t)row * 512 + k0 + u * 8];
        }
        __syncthreads();

        bfrag af[4], bfv[8];
#pragma unroll
        for (int mm = 0; mm < 4; mm++) {
            int row = wm * 64 + mm * 16 + lr;
            af[mm] = *(const bfrag*)&As[row * 32 + (lg ^ (row & 3)) * 8];
        }
#pragma unroll
        for (int nn = 0; nn < 8; nn++) {
            int row = wn * 128 + nn * 16 + lr;
            bfv[nn] = *(const bfrag*)&Bs[row * 32 + (lg ^ (row & 3)) * 8];
        }
#pragma unroll
        for (int mm = 0; mm < 4; mm++)
#pragma unroll
            for (int nn = 0; nn < 8; nn++)
                acc[mm][nn] = __builtin_amdgcn_mfma_f32_16x16x32_bf16(af[mm], bfv[nn], acc[mm][nn], 0, 0, 0);
        __syncthreads();
    }

    float bUi[8], bUj[8];
#pragma unroll
    for (int nn = 0; nn < 8; nn++) {
        int col = wn * 128 + nn * 16 + lr;
        bUi[nn] = biasUi[col];
        bUj[nn] = uj1_b[col];
    }
#pragma unroll
    for (int mm = 0; mm < 4; mm++) {
#pragma unroll
        for (int r = 0; r < 4; r++) {
            int row = tM + wm * 64 + mm * 16 + lg * 4 + r;
            int c = colof[row];
            float s = valof[row];
            float sA = sumA[row];
#pragma unroll
            for (int nn = 0; nn < 8; nn++) {
                int col = wn * 128 + nn * 16 + lr;
                float v = acc[mm][nn][r] + bUi[nn] + sA * bUj[nn]
                        + s * bf2f(XW[(size_t)c * 256 + col]);
                out[(size_t)row * 256 + col] = v;
            }
        }
    }
}

// ---------------------------------------------------------------------------
// Host launcher
// ---------------------------------------------------------------------------
extern "C" void kernel_launch(void* const* d_in, const int* in_sizes, int n_in,
                              void* d_out, int out_size, void* d_ws, size_t ws_size,
                              hipStream_t stream)
{
    const float* x      = (const float*)d_in[0];
    const int*   up_row = (const int*)  d_in[1];
    const int*   up_col = (const int*)  d_in[2];
    const float* up_val = (const float*)d_in[3];
    const int*   e_src  = (const int*)  d_in[4];
    const int*   e_dst  = (const int*)  d_in[5];
    const float* adjv   = (const float*)d_in[6];
    const float* W_res  = (const float*)d_in[7];
    const float* b_res  = (const float*)d_in[8];
    const float* bn0_g  = (const float*)d_in[9];
    const float* bn0_b  = (const float*)d_in[10];
    const float* bn1_g  = (const float*)d_in[11];
    const float* bn1_b  = (const float*)d_in[12];
    const float* Ui0_W  = (const float*)d_in[13];
    const float* Ui0_b  = (const float*)d_in[14];
    const float* Uj0_W  = (const float*)d_in[15];
    const float* Uj0_b  = (const float*)d_in[16];
    const float* Ui1_W  = (const float*)d_in[17];
    const float* Ui1_b  = (const float*)d_in[18];
    const float* Uj1_W  = (const float*)d_in[19];
    const float* Uj1_b  = (const float*)d_in[20];

    float* out = (float*)d_out;

    // ---- workspace layout ----
    char* ws = (char*)d_ws;
    size_t off = 0;
    auto alloc = [&](size_t bytes) -> char* {
        char* p = ws + off;
        off = (off + bytes + 255) & ~(size_t)255;
        return p;
    };
    ushort* XW    = (ushort*)alloc((size_t)V_PREV * F_OUT * 2);   // 8.4 MB
    ushort* XNJ   = (ushort*)alloc((size_t)V_PREV * F_OUT * 2);   // 8.4 MB
    ushort* XNI   = (ushort*)alloc((size_t)V_PREV * F_OUT * 2);   // 8.4 MB
    ushort* X1    = (ushort*)alloc((size_t)V_NEXT * F_OUT * 2);   // 33.6 MB
    ushort* G     = (ushort*)alloc((size_t)V_NEXT * F_OUT * 2);   // 33.6 MB
    // --- zeroed region (prep_all): cnt, psum1s, psq1s (98304 ints) ---
    int*    cnt   = (int*)   alloc(V_NEXT * 4);                   // 256 KB
    float*  psum1s= (float*) alloc(64 * 256 * 4);                 // 64 KB
    float*  psq1s = (float*) alloc(64 * 256 * 4);                 // 64 KB
    float*  sumA  = (float*) alloc(V_NEXT * 4);
    int*    offs  = (int*)   alloc(V_NEXT * 4);
    int*    cursor= (int*)   alloc(V_NEXT * 4);
    int*    bsum  = (int*)   alloc(256 * 4);
    int4*   E     = (int4*)  alloc((size_t)N_EDGE * 16);          // 8.4 MB
    int*    colof = (int*)   alloc(V_NEXT * 4);
    float*  valof = (float*) alloc(V_NEXT * 4);
    ushort* WresT = (ushort*)alloc(256 * 512 * 2);
    ushort* W0t   = (ushort*)alloc(512 * 512 * 2);
    ushort* W1cat = (ushort*)alloc(256 * 512 * 2);
    float*  biasUi= (float*) alloc(256 * 4);
    float*  psum0 = (float*) alloc(512 * 512 * 4);                // 1 MB
    float*  psq0  = (float*) alloc(512 * 512 * 4);                // 1 MB
    float*  sc0   = (float*) alloc(512 * 4);
    float*  sh0   = (float*) alloc(512 * 4);
    float*  sc1   = (float*) alloc(256 * 4);
    float*  sh1   = (float*) alloc(256 * 4);
    (void)ws_size; (void)in_sizes; (void)n_in; (void)out_size;

    // ---- K1: weight prep + up invert + zero counters ----
    prep_all_kernel<<<1664, 256, 0, stream>>>(W_res, Ui0_W, Uj0_W, Ui1_W, Uj1_W,
                                              Ui1_b, b_res,
                                              up_row, up_col, up_val,
                                              WresT, W0t, W1cat, biasUi,
                                              colof, valof, cnt);

    // ---- K2: histogram (cnt only) + bn0 partial stats (512 blocks) ----
    hist_bn0_kernel<<<2560, 256, 0, stream>>>(e_dst, cnt, x, psum0, psq0);

    // ---- K3: block scan ----
    scan_block_kernel<<<256, 256, 0, stream>>>(cnt, offs, bsum);

    // ---- K4: offset add + bn0 finish ----
    add_offs_bnfin_kernel<<<384, 256, 0, stream>>>(offs, bsum, cursor,
                                                   psum0, psq0, bn0_g, bn0_b, sc0, sh0);

    // ---- K5: edge fill (packed int4) + GEMM0 fused ----
    fill_gemm0_kernel<<<2816, 256, 0, stream>>>(e_src, e_dst, adjv, colof, valof,
                                                cursor, E,
                                                x, WresT, W0t, sc0, sh0,
                                                XW, XNJ, XNI);

    // ---- K6: ECC layer 0 aggregation + sumA + bn1 stats (persistent) ----
    gather0_kernel<<<2048, 256, 0, stream>>>(offs, cnt, E, colof, valof,
                                             XNJ, XNI, Ui0_b, Uj0_b,
                                             X1, sumA, psum1s, psq1s);

    // ---- K7: bn1 finish ----
    bn_finish_kernel<<<64, 256, 0, stream>>>(psum1s, psq1s, 64, 256, 1.0f / V_NEXT,
                                             bn1_g, bn1_b, sc1, sh1);

    // ---- K8: ECC layer 1 aggregation (commuted) ----
    gather1G_kernel<<<V_NEXT / 4, 256, 0, stream>>>(offs, cnt, E, X1, sc1, sh1, G);

    // ---- K9: final GEMM: out = [H1|G] @ W1cat + biases + residual ----
    gemm_final_kernel<<<256, 512, 0, stream>>>(X1, G, W1cat, sc1, sh1,
                                               biasUi, Uj1_b, sumA,
                                               colof, valof, XW, out);
}